// Round 11
// baseline (674.075 us; speedup 1.0000x reference)
//
#include <hip/hip_runtime.h>
#include <hip/hip_bf16.h>

// MoE (img/txt mixture) transformer block for MI355X.
// Round 11: gemm8 K-loop software-pipelined at register level. BK=32,
// 2x32KB LDS buffers, double frag sets: reads for tile t+1 issue BEFORE
// tile t's 32-MFMA cluster (no lgkm in between) -> LDS reads hide under
// MFMA instead of adding. BAR1 -> stage(t+2) -> vmcnt(4) -> BAR2 ->
// issue-reads(t+1) -> MFMA(t) -> lgkmcnt(0). Host structure = r9 (622us).

typedef __hip_bfloat16 bf16;
typedef __attribute__((ext_vector_type(8))) __bf16 bf16x8;
typedef __attribute__((ext_vector_type(4))) float f32x4;

#define DEV __device__ __forceinline__

static constexpr int TT = 1536;
static constexpr int NHQ = 16, NKVH = 8, HDM = 128;

DEV void async_load16(const void* g, void* l) {
  typedef const __attribute__((address_space(1))) void* gas_t;
  typedef __attribute__((address_space(3))) void* las_t;
  __builtin_amdgcn_global_load_lds((gas_t)g, (las_t)l, 16, 0, 0);
}

DEV f32x4 mfma16(bf16x8 a, bf16x8 b, f32x4 c) {
  return __builtin_amdgcn_mfma_f32_16x16x32_bf16(a, b, c, 0, 0, 0);
}

DEV float bf2f(bf16 x) { return __bfloat162float(x); }
DEV bf16  f2bf(float x) { return __float2bfloat16(x); }

// ---------------------------------------------------------------------------
// Weight transpose+convert: f32 [K][N] -> bf16 [N][K]
// ---------------------------------------------------------------------------
struct TJob { const float* src; bf16* dst; int K; int N; };
struct TJobs { TJob j[14]; int cum[15]; };

__global__ __launch_bounds__(256) void wt_transpose(TJobs P) {
  __shared__ bf16 tile[64][65];
  int bid = blockIdx.x;
  int ji = 0;
  while (ji < 13 && bid >= P.cum[ji + 1]) ji++;
  const TJob jb = P.j[ji];
  int rel = bid - P.cum[ji];
  int ntc = jb.N >> 6;
  int tr = rel / ntc, tc = rel - tr * ntc;
  int r0 = tr << 6, c0 = tc << 6;
  int t = threadIdx.x;
  #pragma unroll
  for (int i = 0; i < 16; i++) {
    int idx = i * 256 + t;
    int r = idx >> 6, c = idx & 63;
    tile[c][r] = f2bf(jb.src[(size_t)(r0 + r) * jb.N + c0 + c]);
  }
  __syncthreads();
  #pragma unroll
  for (int i = 0; i < 16; i++) {
    int idx = i * 256 + t;
    int r = idx >> 6, c = idx & 63;
    jb.dst[(size_t)(c0 + r) * jb.K + r0 + c] = tile[r][c];
  }
}

// bf16 transpose for V: v_all [B*TT][NKVH*HDM] -> vt [B*NKVH][HDM][TT]
__global__ __launch_bounds__(256) void transpose_v(const bf16* __restrict__ v_all,
                                                   bf16* __restrict__ vt) {
  int st = blockIdx.x, ht = blockIdx.y, bk = blockIdx.z;
  int b = bk >> 3, kv = bk & 7;
  __shared__ bf16 tile[64][65];
  int t = threadIdx.x;
  int s0 = st * 64, h0 = ht * 64;
  #pragma unroll
  for (int i = 0; i < 16; i++) {
    int idx = i * 256 + t;
    int r = idx >> 6, c = idx & 63;
    tile[c][r] = v_all[((size_t)(b * TT + s0 + r) * NKVH + kv) * HDM + h0 + c];
  }
  __syncthreads();
  #pragma unroll
  for (int i = 0; i < 16; i++) {
    int idx = i * 256 + t;
    int r = idx >> 6, c = idx & 63;
    vt[((size_t)bk * HDM + h0 + r) * TT + s0 + c] = tile[r][c];
  }
}

// ---------------------------------------------------------------------------
// RMSNorm (single input)
// ---------------------------------------------------------------------------
template <int DV>
__global__ __launch_bounds__(256) void rmsnorm_k(const float* __restrict__ x,
                                                 const float* __restrict__ sc,
                                                 bf16* __restrict__ out) {
  const int D = DV * 1024;
  int row = blockIdx.x, t = threadIdx.x;
  const float4* xr = reinterpret_cast<const float4*>(x + (size_t)row * D);
  float4 v[DV];
  float ss = 0.f;
  #pragma unroll
  for (int i = 0; i < DV; i++) {
    v[i] = xr[t + i * 256];
    ss += v[i].x * v[i].x + v[i].y * v[i].y + v[i].z * v[i].z + v[i].w * v[i].w;
  }
  #pragma unroll
  for (int o = 1; o < 64; o <<= 1) ss += __shfl_xor(ss, o);
  __shared__ float red[4];
  if ((t & 63) == 0) red[t >> 6] = ss;
  __syncthreads();
  float r = rsqrtf((red[0] + red[1] + red[2] + red[3]) * (1.0f / D) + 1e-6f);
  bf16* orow = out + (size_t)row * D;
  #pragma unroll
  for (int i = 0; i < DV; i++) {
    int c = (t + i * 256) * 4;
    orow[c + 0] = f2bf(v[i].x * r * (1.f + sc[c + 0]));
    orow[c + 1] = f2bf(v[i].y * r * (1.f + sc[c + 1]));
    orow[c + 2] = f2bf(v[i].z * r * (1.f + sc[c + 2]));
    orow[c + 3] = f2bf(v[i].w * r * (1.f + sc[c + 3]));
  }
}

// ---------------------------------------------------------------------------
// RMSNorm over (p0+p1+x): fused wo split-K=2 reduce + pre-FFW norm
// ---------------------------------------------------------------------------
template <int DV>
__global__ __launch_bounds__(256) void rmsnorm2_k(
    const float* __restrict__ p0, const float* __restrict__ p1,
    const float* __restrict__ x, const float* __restrict__ sc,
    bf16* __restrict__ out) {
  const int D = DV * 1024;
  int row = blockIdx.x, t = threadIdx.x;
  size_t rb = (size_t)row * (D / 4);
  const float4* r0 = reinterpret_cast<const float4*>(p0) + rb;
  const float4* r1 = reinterpret_cast<const float4*>(p1) + rb;
  const float4* xr = reinterpret_cast<const float4*>(x) + rb;
  float4 v[DV];
  float ss = 0.f;
  #pragma unroll
  for (int i = 0; i < DV; i++) {
    int idx = t + i * 256;
    float4 a = r0[idx], b = r1[idx], e = xr[idx];
    v[i] = make_float4(a.x + b.x + e.x, a.y + b.y + e.y,
                       a.z + b.z + e.z, a.w + b.w + e.w);
    ss += v[i].x * v[i].x + v[i].y * v[i].y + v[i].z * v[i].z + v[i].w * v[i].w;
  }
  #pragma unroll
  for (int o = 1; o < 64; o <<= 1) ss += __shfl_xor(ss, o);
  __shared__ float red[4];
  if ((t & 63) == 0) red[t >> 6] = ss;
  __syncthreads();
  float r = rsqrtf((red[0] + red[1] + red[2] + red[3]) * (1.0f / D) + 1e-6f);
  bf16* orow = out + (size_t)row * D;
  #pragma unroll
  for (int i = 0; i < DV; i++) {
    int c = (t + i * 256) * 4;
    orow[c + 0] = f2bf(v[i].x * r * (1.f + sc[c + 0]));
    orow[c + 1] = f2bf(v[i].y * r * (1.f + sc[c + 1]));
    orow[c + 2] = f2bf(v[i].z * r * (1.f + sc[c + 2]));
    orow[c + 3] = f2bf(v[i].w * r * (1.f + sc[c + 3]));
  }
}

// ---------------------------------------------------------------------------
// RoPE in-place
// ---------------------------------------------------------------------------
__global__ __launch_bounds__(256) void rope_inplace(bf16* __restrict__ x, int lognh,
                                                    float scale) {
  int gid = blockIdx.x * 256 + threadIdx.x;
  int i = gid & 63;
  int rh = gid >> 6;
  int row = rh >> lognh;
  int pos = row >= TT ? row - TT : row;
  float fr = expf(-9.210340371976184f * ((float)(2 * i) * (1.0f / 128.0f)));
  float th = (float)pos * fr;
  float s, c;
  sincosf(th, &s, &c);
  bf16* p = x + (size_t)rh * HDM;
  float x1 = bf2f(p[i]), x2 = bf2f(p[i + 64]);
  p[i]      = f2bf((x1 * c - x2 * s) * scale);
  p[i + 64] = f2bf((x2 * c + x1 * s) * scale);
}

// ---------------------------------------------------------------------------
// 256x256 GEMM, BK=32, register-pipelined: reads for tile t+1 overlap
// the 32-MFMA cluster of tile t. 2 LDS buffers of 32KB.
// ---------------------------------------------------------------------------
struct G8Job {
  const bf16* A; const bf16* B; bf16* Cb; float* Cf;
  int K, N, lda, ldb;
  int a_base, a_lsh, a_lskip;
  int c_base, c_lsh, c_lskip, c_stride;
};
struct G8Jobs { G8Job j[8]; int cum[9]; int nj; };

#define G8_READ(T, FA, FB)                                              \
  {                                                                     \
    const bf16* bufA_ = lds8 + ((T) & 1) * 16384;                       \
    const bf16* bufB_ = bufA_ + 8192;                                   \
    _Pragma("unroll")                                                   \
    for (int i_ = 0; i_ < 8; i_++)                                      \
      FA[i_] = *reinterpret_cast<const bf16x8*>(                        \
          bufA_ + (arow + i_ * 16) * 32 + sA);                          \
    _Pragma("unroll")                                                   \
    for (int n_ = 0; n_ < 4; n_++)                                      \
      FB[n_] = *reinterpret_cast<const bf16x8*>(                        \
          bufB_ + (brow + n_ * 16) * 32 + sA);                          \
  }

#define G8_MFMA32(FA, FB)                                               \
  {                                                                     \
    __builtin_amdgcn_s_setprio(1);                                      \
    _Pragma("unroll")                                                   \
    for (int i_ = 0; i_ < 8; i_++)                                      \
      _Pragma("unroll")                                                 \
      for (int n_ = 0; n_ < 4; n_++)                                    \
        acc[i_][n_] = mfma16(FA[i_], FB[n_], acc[i_][n_]);              \
    __builtin_amdgcn_s_setprio(0);                                      \
  }

#define G8_STEP(T, FAc, FBc, FAn, FBn)                                  \
  {                                                                     \
    __builtin_amdgcn_s_barrier();                                       \
    asm volatile("" ::: "memory");                                      \
    if ((T) + 2 < nk) {                                                 \
      stage((T) + 2);                                                   \
      asm volatile("s_waitcnt vmcnt(4)" ::: "memory");                  \
    } else if ((T) + 2 == nk) {                                         \
      asm volatile("s_waitcnt vmcnt(0)" ::: "memory");                  \
    }                                                                   \
    if ((T) + 1 < nk) {                                                 \
      __builtin_amdgcn_s_barrier();                                     \
      asm volatile("" ::: "memory");                                    \
      G8_READ((T) + 1, FAn, FBn)                                       \
    }                                                                   \
    __builtin_amdgcn_sched_barrier(0);                                  \
    G8_MFMA32(FAc, FBc)                                                 \
    asm volatile("s_waitcnt lgkmcnt(0)" ::: "memory");                  \
    __builtin_amdgcn_sched_barrier(0);                                  \
  }

__global__ __launch_bounds__(512, 2) void gemm8(G8Jobs P) {
  extern __shared__ __align__(16) bf16 lds8[];  // 2 x (8192 A + 8192 B) elems
  int bid = blockIdx.x;
  int ji = 0;
  while (ji < P.nj - 1 && bid >= P.cum[ji + 1]) ji++;
  const G8Job jb = P.j[ji];
  int rel = bid - P.cum[ji];
  int tn = jb.N >> 8;
  int bm = rel / tn, bn = rel - bm * tn;
  const int m0 = bm << 8, n0 = bn << 8;
  const int nk = jb.K >> 5;

  const int tid = threadIdx.x;
  const int w = tid >> 6, l = tid & 63;
  const int lr = l & 15, lk = l >> 4;
  const int wr = w >> 2, wc = w & 3;

  const int wbase = w * 64;

  // stage tile ht: A rows m0..m0+255 and B rows n0..n0+255, K-slice 32.
  // LDS layout: row*32 elems, 16B slot s at ((s ^ (row&3))<<3) (src pre-swz).
  auto stage = [&](int ht) {
    int k0 = ht << 5;
    bf16* ldsb = lds8 + (ht & 1) * 16384;
    #pragma unroll
    for (int j = 0; j < 2; j++) {
      int idx = j * 512 + tid;
      int row = idx >> 2;
      int sw = ((idx & 3) ^ (row & 3)) << 3;
      int mr = m0 + row;
      int pr = jb.a_base + mr + ((mr >> jb.a_lsh) * jb.a_lskip);
      async_load16(jb.A + (size_t)pr * jb.lda + k0 + sw,
                   ldsb + (j * 512 + wbase) * 8);
      async_load16(jb.B + (size_t)(n0 + row) * jb.ldb + k0 + sw,
                   ldsb + 8192 + (j * 512 + wbase) * 8);
    }
  };

  f32x4 acc[8][4];
  #pragma unroll
  for (int i = 0; i < 8; i++)
    #pragma unroll
    for (int j = 0; j < 4; j++) acc[i][j] = (f32x4){0.f, 0.f, 0.f, 0.f};

  const int arow = wr * 128 + lr;
  const int brow = wc * 64 + lr;
  const int sA = (lk ^ (lr & 3)) << 3;

  bf16x8 fa0[8], fb0[4], fa1[8], fb1[4];

  // prologue: stage tiles 0,1; wait tile 0; read frags[0]
  stage(0);
  stage(1);
  asm volatile("s_waitcnt vmcnt(4)" ::: "memory");
  __builtin_amdgcn_s_barrier();
  asm volatile("" ::: "memory");
  G8_READ(0, fa0, fb0)
  asm volatile("s_waitcnt lgkmcnt(0)" ::: "memory");
  __builtin_amdgcn_sched_barrier(0);

  for (int t = 0; t < nk; t += 2) {
    G8_STEP(t,     fa0, fb0, fa1, fb1)
    G8_STEP(t + 1, fa1, fb1, fa0, fb0)
  }

  if (jb.Cf) {
    #pragma unroll
    for (int mi = 0; mi < 8; mi++)
      #pragma unroll
      for (int jj = 0; jj < 4; jj++) {
        int m = m0 + wr * 128 + mi * 16 + lk * 4 + jj;
        float* drow = jb.Cf + (size_t)m * jb.c_stride + n0 + wc * 64;
        #pragma unroll
        for (int ni = 0; ni < 4; ni++) drow[ni * 16 + lr] = acc[mi][ni][jj];
      }
  } else {
    #pragma unroll
    for (int mi = 0; mi < 8; mi++)
      #pragma unroll
      for (int jj = 0; jj < 4; jj++) {
        int m = m0 + wr * 128 + mi * 16 + lk * 4 + jj;
        int crow = jb.c_base + m + ((m >> jb.c_lsh) * jb.c_lskip);
        bf16* drow = jb.Cb + (size_t)crow * jb.c_stride + n0 + wc * 64;
        #pragma unroll
        for (int ni = 0; ni < 4; ni++) drow[ni * 16 + lr] = f2bf(acc[mi][ni][jj]);
      }
  }
}

// ---------------------------------------------------------------------------
// Down split-K reduce: img out += p1+p2+p3+x ; txt out += q1..q7+x
// ---------------------------------------------------------------------------
__global__ __launch_bounds__(256) void reduce_down(
    float* __restrict__ oi, const float* __restrict__ a1,
    const float* __restrict__ a2, const float* __restrict__ a3,
    const float* __restrict__ xi, int n4i,
    float* __restrict__ ot, const float* __restrict__ b1,
    const float* __restrict__ b2, const float* __restrict__ b3,
    const float* __restrict__ b4, const float* __restrict__ b5,
    const float* __restrict__ b6, const float* __restrict__ b7,
    const float* __restrict__ xt, int n4t) {
  int tot = n4i + n4t;
  for (int idx = blockIdx.x * 256 + threadIdx.x; idx < tot; idx += gridDim.x * 256) {
    if (idx < n4i) {
      float4 d = ((const float4*)oi)[idx];
      float4 a = ((const float4*)a1)[idx];
      float4 b = ((const float4*)a2)[idx];
      float4 c = ((const float4*)a3)[idx];
      float4 e = ((const float4*)xi)[idx];
      ((float4*)oi)[idx] = make_float4(d.x + a.x + b.x + c.x + e.x,
                                       d.y + a.y + b.y + c.y + e.y,
                                       d.z + a.z + b.z + c.z + e.z,
                                       d.w + a.w + b.w + c.w + e.w);
    } else {
      int i = idx - n4i;
      float4 d = ((const float4*)ot)[i];
      float4 p1 = ((const float4*)b1)[i];
      float4 p2 = ((const float4*)b2)[i];
      float4 p3 = ((const float4*)b3)[i];
      float4 p4 = ((const float4*)b4)[i];
      float4 p5 = ((const float4*)b5)[i];
      float4 p6 = ((const float4*)b6)[i];
      float4 p7 = ((const float4*)b7)[i];
      float4 e = ((const float4*)xt)[i];
      ((float4*)ot)[i] = make_float4(
          d.x + p1.x + p2.x + p3.x + p4.x + p5.x + p6.x + p7.x + e.x,
          d.y + p1.y + p2.y + p3.y + p4.y + p5.y + p6.y + p7.y + e.y,
          d.z + p1.z + p2.z + p3.z + p4.z + p5.z + p6.z + p7.z + e.z,
          d.w + p1.w + p2.w + p3.w + p4.w + p5.w + p6.w + p7.w + e.w);
    }
  }
}

// ---------------------------------------------------------------------------
// In-place GELU(gate)*up over gu buffers: act written to gate half.
// ---------------------------------------------------------------------------
__global__ __launch_bounds__(256) void gelu_mul(bf16* __restrict__ gu_i,
                                                bf16* __restrict__ gu_t) {
  const int IMG_CH = 2048 * 8192 / 8;
  const int TXT_CH = 1024 * 4096 / 8;
  int idx = blockIdx.x * 256 + threadIdx.x;
  int total = IMG_CH + TXT_CH;
  if (idx >= total) return;
  bf16* base;
  int half, ci;
  if (idx < IMG_CH) { base = gu_i; half = 8192; ci = idx; }
  else              { base = gu_t; half = 4096; ci = idx - IMG_CH; }
  int rowlen = half * 2;
  int perrow = half / 8;
  int m = ci / perrow, n8 = ci - m * perrow;
  bf16* gp = base + (size_t)m * rowlen + n8 * 8;
  bf16* up = gp + half;
  bf16x8 g8 = *reinterpret_cast<const bf16x8*>(gp);
  bf16x8 u8 = *reinterpret_cast<const bf16x8*>(up);
  bf16x8 o8;
  #pragma unroll
  for (int i = 0; i < 8; i++) {
    float g = (float)g8[i], u = (float)u8[i];
    float t = tanhf(0.7978845608028654f * (g + 0.044715f * g * g * g));
    o8[i] = (__bf16)(0.5f * g * (1.f + t) * u);
  }
  *reinterpret_cast<bf16x8*>(gp) = o8;
}

// ---------------------------------------------------------------------------
// Flash attention with softcap (no online max; logits bounded by +-50).
// ---------------------------------------------------------------------------
__global__ __launch_bounds__(256) void attn_k(const bf16* __restrict__ q_all,
                                              const bf16* __restrict__ k_all,
                                              const bf16* __restrict__ vt,
                                              bf16* __restrict__ attn_o) {
  const int qt = blockIdx.x;
  const int n = blockIdx.y;
  const int b = blockIdx.z;
  const int kv = n >> 1;
  const int tid = threadIdx.x, w = tid >> 6, l = tid & 63;
  const int lr = l & 15, lk = l >> 4;
  __shared__ __align__(16) bf16 Ksm[64 * 128];
  __shared__ __align__(16) bf16 Vsm[128 * 64];
  __shared__ __align__(16) bf16 Psm[4][16][72];

  bf16x8 qf[4];
  {
    int t = qt * 64 + w * 16 + lr;
    const bf16* qp = q_all + ((size_t)(b * TT + t) * NHQ + n) * HDM;
    #pragma unroll
    for (int kk = 0; kk < 4; kk++)
      qf[kk] = *reinterpret_cast<const bf16x8*>(qp + kk * 32 + lk * 8);
  }
  f32x4 acc_o[8];
  #pragma unroll
  for (int i = 0; i < 8; i++) acc_o[i] = (f32x4){0.f, 0.f, 0.f, 0.f};
  float den[4] = {0.f, 0.f, 0.f, 0.f};

  for (int st = 0; st < TT / 64; st++) {
    __syncthreads();
    #pragma unroll
    for (int i = 0; i < 4; i++) {
      int cb = (w * 4 + i) * 64;
      int c = cb + l;
      {
        int srow = c >> 4, c16 = c & 15;
        const bf16* g = k_all + ((size_t)(b * TT + st * 64 + srow) * NKVH + kv) * HDM +
                        ((c16 ^ (srow & 7)) << 3);
        async_load16(g, Ksm + cb * 8);
      }
      {
        int hrow = c >> 3, c8 = c & 7;
        const bf16* g = vt + ((size_t)(b * NKVH + kv) * HDM + hrow) * TT + st * 64 +
                        ((c8 ^ (hrow & 7)) << 3);
        async_load16(g, Vsm + cb * 8);
      }
    }
    __syncthreads();
    #pragma unroll
    for (int sf = 0; sf < 4; sf++) {
      f32x4 s4 = (f32x4){0.f, 0.f, 0.f, 0.f};
      int sl = sf * 16 + lr;
      #pragma unroll
      for (int kk = 0; kk < 4; kk++) {
        int e = kk * 32 + lk * 8;
        bf16x8 kf = *reinterpret_cast<const bf16x8*>(
            Ksm + sl * 128 + ((((e >> 3) ^ (sl & 7))) << 3));
        s4 = mfma16(qf[kk], kf, s4);
      }
      #pragma unroll
      for (int j = 0; j < 4; j++) {
        float xv = s4[j];
        float tcap = tanhf(xv * 0.02f) * 50.f;
        float p = __expf(tcap);
        Psm[w][lk * 4 + j][sf * 16 + lr] = f2bf(p);
        p += __shfl_xor(p, 1);
        p += __shfl_xor(p, 2);
        p += __shfl_xor(p, 4);
        p += __shfl_xor(p, 8);
        den[j] += p;
      }
    }
    #pragma unroll
    for (int kk2 = 0; kk2 < 2; kk2++) {
      bf16x8 pa = *reinterpret_cast<const bf16x8*>(&Psm[w][lr][kk2 * 32 + lk * 8]);
      #pragma unroll
      for (int hf = 0; hf < 8; hf++) {
        int h = hf * 16 + lr;
        int e2 = kk2 * 32 + lk * 8;
        bf16x8 vb = *reinterpret_cast<const bf16x8*>(
            Vsm + h * 64 + ((((e2 >> 3) ^ (h & 7))) << 3));
        acc_o[hf] = mfma16(pa, vb, acc_o[hf]);
      }
    }
  }
  #pragma unroll
  for (int hf = 0; hf < 8; hf++)
    #pragma unroll
    for (int j = 0; j < 4; j++) {
      int t = qt * 64 + w * 16 + lk * 4 + j;
      float val = acc_o[hf][j] / den[j];
      attn_o[((size_t)(b * TT + t)) * (NHQ * HDM) + n * HDM + hf * 16 + lr] = f2bf(val);
    }
}

// ---------------------------------------------------------------------------
extern "C" void kernel_launch(void* const* d_in, const int* in_sizes, int n_in,
                              void* d_out, int out_size, void* d_ws,
                              size_t ws_size, hipStream_t stream) {
  const float* x_img = (const float*)d_in[0];
  const float* x_txt = (const float*)d_in[1];
  const float* sc_attn_i = (const float*)d_in[3];
  const float* wq_i = (const float*)d_in[4];
  const float* wk_i = (const float*)d_in[5];
  const float* wv_i = (const float*)d_in[6];
  const float* wo_i = (const float*)d_in[7];
  const float* sc_ffw_i = (const float*)d_in[8];
  const float* wg_i = (const float*)d_in[9];
  const float* wu_i = (const float*)d_in[10];
  const float* wd_i = (const float*)d_in[11];
  const float* sc_attn_t = (const float*)d_in[12];
  const float* wq_t = (const float*)d_in[13];
  const float* wk_t = (const float*)d_in[14];
  const float* wv_t = (const float*)d_in[15];
  const float* wo_t = (const float*)d_in[16];
  const float* sc_ffw_t = (const float*)d_in[17];
  const float* wg_t = (const float*)d_in[18];
  const float* wu_t = (const float*)d_in[19];
  const float* wd_t = (const float*)d_in[20];
  float* outp = (float*)d_out;
  float* outp_t = outp + (size_t)2 * 1024 * 2048;

  char* ws = (char*)d_ws;
  size_t off = 0;
  auto alloc = [&](size_t n) {
    char* p = ws + off;
    off += (n + 255) & ~(size_t)255;
    return p;
  };
  bf16* WqT_i = (bf16*)alloc((size_t)2048 * 2048 * 2);
  bf16* WkT_i = (bf16*)alloc((size_t)1024 * 2048 * 2);
  bf16* WvT_i = (bf16*)alloc((size_t)1024 * 2048 * 2);
  bf16* WoT_i = (bf16*)alloc((size_t)2048 * 2048 * 2);
  bf16* WguT_i = (bf16*)alloc((size_t)16384 * 2048 * 2);  // 64 MB
  bf16* WdT_i = (bf16*)alloc((size_t)2048 * 8192 * 2);
  bf16* WqT_t = (bf16*)alloc((size_t)2048 * 1024 * 2);
  bf16* WkT_t = (bf16*)alloc((size_t)1024 * 1024 * 2);
  bf16* WvT_t = (bf16*)alloc((size_t)1024 * 1024 * 2);
  bf16* WoT_t = (bf16*)alloc((size_t)1024 * 2048 * 2);
  bf16* WguT_t = (bf16*)alloc((size_t)8192 * 1024 * 2);   // 16 MB
  bf16* WdT_t = (bf16*)alloc((size_t)1024 * 4096 * 2);
  bf16* xn_i = (bf16*)alloc((size_t)2048 * 2048 * 2);
  bf16* xn_t = (bf16*)alloc((size_t)1024 * 1024 * 2);
  float* h_i = (float*)alloc((size_t)2048 * 2048 * 4);  // wo p0 img
  float* h_t = (float*)alloc((size_t)1024 * 1024 * 4);  // wo p0 txt
  char* S = (char*)alloc((size_t)84 * 1024 * 1024);
  (void)ws_size;

  const size_t MB = 1024 * 1024;
  bf16* q_all = (bf16*)S;
  bf16* k_all = (bf16*)(S + 12 * MB);
  bf16* v_all = (bf16*)(S + 18 * MB);
  bf16* vtr   = (bf16*)(S + 24 * MB);
  bf16* attn_o= (bf16*)(S + 30 * MB);
  float* wp1_i = (float*)S;
  float* wp1_t = (float*)(S + 16 * MB);
  bf16* gu_i  = (bf16*)S;
  bf16* gu_t  = (bf16*)(S + 64 * MB);
  float* dp1 = (float*)WguT_i;
  float* dp2 = (float*)((char*)WguT_i + 16 * MB);
  float* dp3 = (float*)((char*)WguT_i + 32 * MB);
  float* dt1 = (float*)((char*)WguT_i + 48 * MB);
  float* dt2 = (float*)((char*)WguT_i + 52 * MB);
  float* dt3 = (float*)((char*)WguT_i + 56 * MB);
  float* dt4 = (float*)((char*)WguT_i + 60 * MB);
  float* dt5 = (float*)WguT_t;
  float* dt6 = (float*)((char*)WguT_t + 4 * MB);
  float* dt7 = (float*)((char*)WguT_t + 8 * MB);

  (void)hipFuncSetAttribute(reinterpret_cast<const void*>(gemm8),
                            hipFuncAttributeMaxDynamicSharedMemorySize, 65536);

  // 1. weight transpose/convert
  TJobs tj;
  auto setj = [&](int idx, const float* s, bf16* d, int K, int N) {
    tj.j[idx].src = s; tj.j[idx].dst = d; tj.j[idx].K = K; tj.j[idx].N = N;
  };
  setj(0, wq_i, WqT_i, 2048, 2048);
  setj(1, wk_i, WkT_i, 2048, 1024);
  setj(2, wv_i, WvT_i, 2048, 1024);
  setj(3, wo_i, WoT_i, 2048, 2048);
  setj(4, wg_i, WguT_i, 2048, 8192);
  setj(5, wu_i, WguT_i + (size_t)8192 * 2048, 2048, 8192);
  setj(6, wd_i, WdT_i, 8192, 2048);
  setj(7, wq_t, WqT_t, 1024, 2048);
  setj(8, wk_t, WkT_t, 1024, 1024);
  setj(9, wv_t, WvT_t, 1024, 1024);
  setj(10, wo_t, WoT_t, 2048, 1024);
  setj(11, wg_t, WguT_t, 1024, 4096);
  setj(12, wu_t, WguT_t + (size_t)4096 * 1024, 1024, 4096);
  setj(13, wd_t, WdT_t, 4096, 1024);
  tj.cum[0] = 0;
  for (int i = 0; i < 14; i++)
    tj.cum[i + 1] = tj.cum[i] + (tj.j[i].K >> 6) * (tj.j[i].N >> 6);
  wt_transpose<<<tj.cum[14], 256, 0, stream>>>(tj);

  // 2. pre-attn RMSNorm
  rmsnorm_k<2><<<2048, 256, 0, stream>>>(x_img, sc_attn_i, xn_i);
  rmsnorm_k<1><<<1024, 256, 0, stream>>>(x_txt, sc_attn_t, xn_t);

  auto mk8b = [](const bf16* A, const bf16* B, bf16* Cb, int K, int N, int lda,
                 int ldb, int ab, int ash, int ask, int cb2, int csh, int csk,
                 int cstr) {
    G8Job g{};
    g.A = A; g.B = B; g.Cb = Cb; g.Cf = nullptr;
    g.K = K; g.N = N; g.lda = lda; g.ldb = ldb;
    g.a_base = ab; g.a_lsh = ash; g.a_lskip = ask;
    g.c_base = cb2; g.c_lsh = csh; g.c_lskip = csk; g.c_stride = cstr;
    return g;
  };
  auto mk8f = [](const bf16* A, const bf16* B, float* Cf, int K, int N, int lda,
                 int ldb, int ab, int ash, int ask, int cstr) {
    G8Job g{};
    g.A = A; g.B = B; g.Cb = nullptr; g.Cf = Cf;
    g.K = K; g.N = N; g.lda = lda; g.ldb = ldb;
    g.a_base = ab; g.a_lsh = ash; g.a_lskip = ask;
    g.c_base = 0; g.c_lsh = 30; g.c_lskip = 0; g.c_stride = cstr;
    return g;
  };
  auto launch8 = [&](G8Jobs& P, int nj, const int* Mt) {
    P.nj = nj;
    P.cum[0] = 0;
    for (int i = 0; i < nj; i++) P.cum[i + 1] = P.cum[i] + Mt[i] * (P.j[i].N >> 8);
    gemm8<<<P.cum[nj], 512, 65536, stream>>>(P);
  };

  // 3. QKV via gemm8
  {
    G8Jobs P;
    P.j[0] = mk8b(xn_i, WqT_i, q_all, 2048, 2048, 2048, 2048, 0, 30, 0, 0, 10, 512, 2048);
    P.j[1] = mk8b(xn_i, WkT_i, k_all, 2048, 1024, 2048, 2048, 0, 30, 0, 0, 10, 512, 1024);
    P.j[2] = mk8b(xn_i, WvT_i, v_all, 2048, 1024, 2048, 2048, 0, 30, 0, 0, 10, 512, 1024);
    P.j[3] = mk8b(xn_t, WqT_t, q_all, 1024, 2048, 1024, 1024, 0, 30, 0, 1024, 9, 1024, 2048);
    P.j[4] = mk8b(xn_t, WkT_t, k_all, 1024, 1024, 1024, 1024, 0, 30, 0, 1024, 9, 1024, 1024);
    P.j[5] = mk8b(xn_t, WvT_t, v_all, 1024, 1024, 1024, 1024, 0, 30, 0, 1024, 9, 1024, 1024);
    int Mt[6] = {8, 8, 8, 4, 4, 4};
    launch8(P, 6, Mt);
  }

  // 4. RoPE
  rope_inplace<<<12288, 256, 0, stream>>>(q_all, 4, 0.08838834764831845f);
  rope_inplace<<<6144, 256, 0, stream>>>(k_all, 3, 1.0f);

  // 5. V transpose
  transpose_v<<<dim3(24, 2, 16), 256, 0, stream>>>(v_all, vtr);

  // 6. attention
  attn_k<<<dim3(24, 16, 2), 256, 0, stream>>>(q_all, k_all, vtr, attn_o);

  // 7. WO split-K=2 (160 blocks): p0 -> h, p1 -> wp1
  {
    G8Jobs P;
    P.j[0] = mk8f(attn_o,        WoT_i,        h_i,   1024, 2048, 2048, 2048, 0, 10, 512, 2048);
    P.j[1] = mk8f(attn_o + 1024, WoT_i + 1024, wp1_i, 1024, 2048, 2048, 2048, 0, 10, 512, 2048);
    P.j[2] = mk8f(attn_o,        WoT_t,        h_t,   1024, 1024, 2048, 2048, 1024, 9, 1024, 1024);
    P.j[3] = mk8f(attn_o + 1024, WoT_t + 1024, wp1_t, 1024, 1024, 2048, 2048, 1024, 9, 1024, 1024);
    int Mt[4] = {8, 8, 4, 4};
    launch8(P, 4, Mt);
  }

  // 8. fused (p0+p1+x) RMSNorm -> xn
  rmsnorm2_k<2><<<2048, 256, 0, stream>>>(h_i, wp1_i, x_img, sc_ffw_i, xn_i);
  rmsnorm2_k<1><<<1024, 256, 0, stream>>>(h_t, wp1_t, x_txt, sc_ffw_t, xn_t);

  // 9. gate|up via gemm8 -> gu (bf16), single launch (640 blocks)
  {
    G8Jobs P;
    P.j[0] = mk8b(xn_i, WguT_i, gu_i, 2048, 16384, 2048, 2048, 0, 30, 0, 0, 30, 0, 16384);
    P.j[1] = mk8b(xn_t, WguT_t, gu_t, 1024, 8192, 1024, 1024, 0, 30, 0, 0, 30, 0, 8192);
    int Mt[2] = {8, 4};
    launch8(P, 2, Mt);
  }
  {
    int total = 2048 * 8192 / 8 + 1024 * 4096 / 8;
    gelu_mul<<<(total + 255) / 256, 256, 0, stream>>>(gu_i, gu_t);
  }

  // 10a. DOWN img split-4 (256 blocks, 1 clean round); p0 -> d_out
  {
    G8Jobs P;
    P.j[0] = mk8f(gu_i,        WdT_i,        outp, 2048, 2048, 16384, 8192, 0, 30, 0, 2048);
    P.j[1] = mk8f(gu_i + 2048, WdT_i + 2048, dp1,  2048, 2048, 16384, 8192, 0, 30, 0, 2048);
    P.j[2] = mk8f(gu_i + 4096, WdT_i + 4096, dp2,  2048, 2048, 16384, 8192, 0, 30, 0, 2048);
    P.j[3] = mk8f(gu_i + 6144, WdT_i + 6144, dp3,  2048, 2048, 16384, 8192, 0, 30, 0, 2048);
    int Mt[4] = {8, 8, 8, 8};
    launch8(P, 4, Mt);
  }
  // 10b. DOWN txt split-8 (128 blocks, short round 2); p0 -> d_out
  {
    G8Jobs P;
    float* dst[8] = {outp_t, dt1, dt2, dt3, dt4, dt5, dt6, dt7};
    for (int s = 0; s < 8; s++)
      P.j[s] = mk8f(gu_t + s * 512, WdT_t + s * 512, dst[s], 512, 1024, 8192,
                    4096, 0, 30, 0, 1024);
    int Mt[8] = {4, 4, 4, 4, 4, 4, 4, 4};
    launch8(P, 8, Mt);
  }
  reduce_down<<<2048, 256, 0, stream>>>(
      outp, dp1, dp2, dp3, x_img, 2048 * 2048 / 4,
      outp_t, dt1, dt2, dt3, dt4, dt5, dt6, dt7, x_txt, 1024 * 1024 / 4);
}

// Round 12
// 610.318 us; speedup vs baseline: 1.1045x; 1.1045x over previous
//
#include <hip/hip_runtime.h>
#include <hip/hip_bf16.h>

// MoE (img/txt mixture) transformer block for MI355X.
// Round 12: gemm8 reverted to r9 (best, 622us). New: FFN-weight transpose
// (gate/up/down, ~315MB, ~50us) fused into the attention launch as extra
// job-table blocks -- attn is latency-bound at 3 blocks/CU and leaves HBM
// idle; transpose blocks backfill. Launch-1 transposes attn weights only.

typedef __hip_bfloat16 bf16;
typedef __attribute__((ext_vector_type(8))) __bf16 bf16x8;
typedef __attribute__((ext_vector_type(4))) float f32x4;

#define DEV __device__ __forceinline__

static constexpr int TT = 1536;
static constexpr int NHQ = 16, NKVH = 8, HDM = 128;

DEV void async_load16(const void* g, void* l) {
  typedef const __attribute__((address_space(1))) void* gas_t;
  typedef __attribute__((address_space(3))) void* las_t;
  __builtin_amdgcn_global_load_lds((gas_t)g, (las_t)l, 16, 0, 0);
}

DEV f32x4 mfma16(bf16x8 a, bf16x8 b, f32x4 c) {
  return __builtin_amdgcn_mfma_f32_16x16x32_bf16(a, b, c, 0, 0, 0);
}

DEV float bf2f(bf16 x) { return __bfloat162float(x); }
DEV bf16  f2bf(float x) { return __float2bfloat16(x); }

// ---------------------------------------------------------------------------
// Weight transpose+convert: f32 [K][N] -> bf16 [N][K]
// ---------------------------------------------------------------------------
struct TJob { const float* src; bf16* dst; int K; int N; };
struct TJobs { TJob j[14]; int cum[15]; };

DEV void wt_body(const TJob& jb, int rel, int t, char* smem) {
  bf16 (*tile)[65] = (bf16 (*)[65])smem;
  int ntc = jb.N >> 6;
  int tr = rel / ntc, tc = rel - tr * ntc;
  int r0 = tr << 6, c0 = tc << 6;
  #pragma unroll
  for (int i = 0; i < 16; i++) {
    int idx = i * 256 + t;
    int r = idx >> 6, c = idx & 63;
    tile[c][r] = f2bf(jb.src[(size_t)(r0 + r) * jb.N + c0 + c]);
  }
  __syncthreads();
  #pragma unroll
  for (int i = 0; i < 16; i++) {
    int idx = i * 256 + t;
    int r = idx >> 6, c = idx & 63;
    jb.dst[(size_t)(c0 + r) * jb.K + r0 + c] = tile[r][c];
  }
}

__global__ __launch_bounds__(256) void wt_transpose(TJobs P) {
  __shared__ __align__(16) char smem[64 * 65 * 2];
  int bid = blockIdx.x;
  int ji = 0;
  while (ji < 13 && bid >= P.cum[ji + 1]) ji++;
  wt_body(P.j[ji], bid - P.cum[ji], threadIdx.x, smem);
}

// bf16 transpose for V: v_all [B*TT][NKVH*HDM] -> vt [B*NKVH][HDM][TT]
__global__ __launch_bounds__(256) void transpose_v(const bf16* __restrict__ v_all,
                                                   bf16* __restrict__ vt) {
  int st = blockIdx.x, ht = blockIdx.y, bk = blockIdx.z;
  int b = bk >> 3, kv = bk & 7;
  __shared__ bf16 tile[64][65];
  int t = threadIdx.x;
  int s0 = st * 64, h0 = ht * 64;
  #pragma unroll
  for (int i = 0; i < 16; i++) {
    int idx = i * 256 + t;
    int r = idx >> 6, c = idx & 63;
    tile[c][r] = v_all[((size_t)(b * TT + s0 + r) * NKVH + kv) * HDM + h0 + c];
  }
  __syncthreads();
  #pragma unroll
  for (int i = 0; i < 16; i++) {
    int idx = i * 256 + t;
    int r = idx >> 6, c = idx & 63;
    vt[((size_t)bk * HDM + h0 + r) * TT + s0 + c] = tile[r][c];
  }
}

// ---------------------------------------------------------------------------
// RMSNorm (single input)
// ---------------------------------------------------------------------------
template <int DV>
__global__ __launch_bounds__(256) void rmsnorm_k(const float* __restrict__ x,
                                                 const float* __restrict__ sc,
                                                 bf16* __restrict__ out) {
  const int D = DV * 1024;
  int row = blockIdx.x, t = threadIdx.x;
  const float4* xr = reinterpret_cast<const float4*>(x + (size_t)row * D);
  float4 v[DV];
  float ss = 0.f;
  #pragma unroll
  for (int i = 0; i < DV; i++) {
    v[i] = xr[t + i * 256];
    ss += v[i].x * v[i].x + v[i].y * v[i].y + v[i].z * v[i].z + v[i].w * v[i].w;
  }
  #pragma unroll
  for (int o = 1; o < 64; o <<= 1) ss += __shfl_xor(ss, o);
  __shared__ float red[4];
  if ((t & 63) == 0) red[t >> 6] = ss;
  __syncthreads();
  float r = rsqrtf((red[0] + red[1] + red[2] + red[3]) * (1.0f / D) + 1e-6f);
  bf16* orow = out + (size_t)row * D;
  #pragma unroll
  for (int i = 0; i < DV; i++) {
    int c = (t + i * 256) * 4;
    orow[c + 0] = f2bf(v[i].x * r * (1.f + sc[c + 0]));
    orow[c + 1] = f2bf(v[i].y * r * (1.f + sc[c + 1]));
    orow[c + 2] = f2bf(v[i].z * r * (1.f + sc[c + 2]));
    orow[c + 3] = f2bf(v[i].w * r * (1.f + sc[c + 3]));
  }
}

// ---------------------------------------------------------------------------
// RMSNorm over (p0+p1+x): fused wo split-K=2 reduce + pre-FFW norm
// ---------------------------------------------------------------------------
template <int DV>
__global__ __launch_bounds__(256) void rmsnorm2_k(
    const float* __restrict__ p0, const float* __restrict__ p1,
    const float* __restrict__ x, const float* __restrict__ sc,
    bf16* __restrict__ out) {
  const int D = DV * 1024;
  int row = blockIdx.x, t = threadIdx.x;
  size_t rb = (size_t)row * (D / 4);
  const float4* r0 = reinterpret_cast<const float4*>(p0) + rb;
  const float4* r1 = reinterpret_cast<const float4*>(p1) + rb;
  const float4* xr = reinterpret_cast<const float4*>(x) + rb;
  float4 v[DV];
  float ss = 0.f;
  #pragma unroll
  for (int i = 0; i < DV; i++) {
    int idx = t + i * 256;
    float4 a = r0[idx], b = r1[idx], e = xr[idx];
    v[i] = make_float4(a.x + b.x + e.x, a.y + b.y + e.y,
                       a.z + b.z + e.z, a.w + b.w + e.w);
    ss += v[i].x * v[i].x + v[i].y * v[i].y + v[i].z * v[i].z + v[i].w * v[i].w;
  }
  #pragma unroll
  for (int o = 1; o < 64; o <<= 1) ss += __shfl_xor(ss, o);
  __shared__ float red[4];
  if ((t & 63) == 0) red[t >> 6] = ss;
  __syncthreads();
  float r = rsqrtf((red[0] + red[1] + red[2] + red[3]) * (1.0f / D) + 1e-6f);
  bf16* orow = out + (size_t)row * D;
  #pragma unroll
  for (int i = 0; i < DV; i++) {
    int c = (t + i * 256) * 4;
    orow[c + 0] = f2bf(v[i].x * r * (1.f + sc[c + 0]));
    orow[c + 1] = f2bf(v[i].y * r * (1.f + sc[c + 1]));
    orow[c + 2] = f2bf(v[i].z * r * (1.f + sc[c + 2]));
    orow[c + 3] = f2bf(v[i].w * r * (1.f + sc[c + 3]));
  }
}

// ---------------------------------------------------------------------------
// RoPE in-place
// ---------------------------------------------------------------------------
__global__ __launch_bounds__(256) void rope_inplace(bf16* __restrict__ x, int lognh,
                                                    float scale) {
  int gid = blockIdx.x * 256 + threadIdx.x;
  int i = gid & 63;
  int rh = gid >> 6;
  int row = rh >> lognh;
  int pos = row >= TT ? row - TT : row;
  float fr = expf(-9.210340371976184f * ((float)(2 * i) * (1.0f / 128.0f)));
  float th = (float)pos * fr;
  float s, c;
  sincosf(th, &s, &c);
  bf16* p = x + (size_t)rh * HDM;
  float x1 = bf2f(p[i]), x2 = bf2f(p[i + 64]);
  p[i]      = f2bf((x1 * c - x2 * s) * scale);
  p[i + 64] = f2bf((x2 * c + x1 * s) * scale);
}

// ---------------------------------------------------------------------------
// 256x256 GEMM - r9 reduced-barrier K-loop (3 barriers/tile). PROVEN 622us.
// ---------------------------------------------------------------------------
struct G8Job {
  const bf16* A; const bf16* B; bf16* Cb; float* Cf;
  int K, N, lda, ldb;
  int a_base, a_lsh, a_lskip;
  int c_base, c_lsh, c_lskip, c_stride;
};
struct G8Jobs { G8Job j[8]; int cum[9]; int nj; };

#define G8_MFMA(MH, NH)                                            \
  __builtin_amdgcn_s_setprio(1);                                   \
  _Pragma("unroll")                                                \
  for (int i = 0; i < 4; i++)                                      \
    _Pragma("unroll")                                              \
    for (int nj2 = 0; nj2 < 2; nj2++)                              \
      _Pragma("unroll")                                            \
      for (int kk = 0; kk < 2; kk++)                               \
        acc[(MH)*4 + i][(NH)*2 + nj2] = mfma16(                    \
            afr[i][kk], bfr[(NH)*2 + nj2][kk],                     \
            acc[(MH)*4 + i][(NH)*2 + nj2]);                        \
  __builtin_amdgcn_s_setprio(0);

__global__ __launch_bounds__(512, 2) void gemm8(G8Jobs P) {
  extern __shared__ __align__(16) bf16 lds8[];
  int bid = blockIdx.x;
  int ji = 0;
  while (ji < P.nj - 1 && bid >= P.cum[ji + 1]) ji++;
  const G8Job jb = P.j[ji];
  int rel = bid - P.cum[ji];
  int tn = jb.N >> 8;
  int bm = rel / tn, bn = rel - bm * tn;
  const int m0 = bm << 8, n0 = bn << 8;
  const int K = jb.K;
  const int nk = K >> 6;

  const int tid = threadIdx.x;
  const int w = tid >> 6, l = tid & 63;
  const int lr = l & 15, lk = l >> 4;
  const int wr = w >> 2, wc = w & 3;

  const int r0 = tid >> 3, sl0 = (tid & 7) ^ (r0 & 7);
  const int dst0 = (w * 64) * 8;
  const int dst1 = (512 + w * 64) * 8;

  auto stage = [&](int ht, int hq) {
    int k0 = ht << 6;
    bf16* ldsb = lds8 + ((ht & 1) * 32768 + hq * 8192);
    if (hq < 2) {
      int ma = m0 + hq * 128;
      int mr0 = ma + r0, mr1 = ma + 64 + r0;
      int pr0 = jb.a_base + mr0 + ((mr0 >> jb.a_lsh) * jb.a_lskip);
      int pr1 = jb.a_base + mr1 + ((mr1 >> jb.a_lsh) * jb.a_lskip);
      async_load16(jb.A + (size_t)pr0 * jb.lda + k0 + sl0 * 8, ldsb + dst0);
      async_load16(jb.A + (size_t)pr1 * jb.lda + k0 + sl0 * 8, ldsb + dst1);
    } else {
      int nb = n0 + (hq - 2) * 128;
      async_load16(jb.B + (size_t)(nb + r0) * jb.ldb + k0 + sl0 * 8, ldsb + dst0);
      async_load16(jb.B + (size_t)(nb + 64 + r0) * jb.ldb + k0 + sl0 * 8, ldsb + dst1);
    }
  };

  f32x4 acc[8][4];
  #pragma unroll
  for (int i = 0; i < 8; i++)
    #pragma unroll
    for (int j = 0; j < 4; j++) acc[i][j] = (f32x4){0.f, 0.f, 0.f, 0.f};

  const int s0 = ((0 * 4 + lk) ^ (lr & 7)) * 8;
  const int s1 = ((1 * 4 + lk) ^ (lr & 7)) * 8;
  const int browb = (wc & 1) * 64;

  #pragma unroll
  for (int hq = 0; hq < 4; hq++) stage(0, hq);
  #pragma unroll
  for (int hq = 0; hq < 4; hq++) stage(1, hq);
  asm volatile("s_waitcnt vmcnt(8)" ::: "memory");
  __builtin_amdgcn_s_barrier();
  asm volatile("" ::: "memory");

  bf16x8 afr[4][2], bfr[4][2];

  for (int t = 0; t < nk; t++) {
    const bf16* bufA = lds8 + (t & 1) * 32768 + wr * 8192;
    const bf16* bufB = lds8 + (t & 1) * 32768 + 16384 + (wc >> 1) * 8192;
    const bool st = (t + 2 < nk);

    #pragma unroll
    for (int i = 0; i < 4; i++) {
      int rb = (i * 16 + lr) * 64;
      afr[i][0] = *reinterpret_cast<const bf16x8*>(bufA + rb + s0);
      afr[i][1] = *reinterpret_cast<const bf16x8*>(bufA + rb + s1);
    }
    #pragma unroll
    for (int ni = 0; ni < 2; ni++) {
      int rb = (browb + ni * 16 + lr) * 64;
      bfr[ni][0] = *reinterpret_cast<const bf16x8*>(bufB + rb + s0);
      bfr[ni][1] = *reinterpret_cast<const bf16x8*>(bufB + rb + s1);
    }
    asm volatile("s_waitcnt lgkmcnt(0)" ::: "memory");
    __builtin_amdgcn_sched_barrier(0);
    G8_MFMA(0, 0)

    #pragma unroll
    for (int ni = 2; ni < 4; ni++) {
      int rb = (browb + ni * 16 + lr) * 64;
      bfr[ni][0] = *reinterpret_cast<const bf16x8*>(bufB + rb + s0);
      bfr[ni][1] = *reinterpret_cast<const bf16x8*>(bufB + rb + s1);
    }
    asm volatile("s_waitcnt lgkmcnt(0)" ::: "memory");
    __builtin_amdgcn_sched_barrier(0);
    G8_MFMA(0, 1)
    __builtin_amdgcn_s_barrier();
    asm volatile("" ::: "memory");

    #pragma unroll
    for (int i = 0; i < 4; i++) {
      int rb = ((i + 4) * 16 + lr) * 64;
      afr[i][0] = *reinterpret_cast<const bf16x8*>(bufA + rb + s0);
      afr[i][1] = *reinterpret_cast<const bf16x8*>(bufA + rb + s1);
    }
    if (st) { stage(t + 2, 2); stage(t + 2, 3); }
    asm volatile("s_waitcnt lgkmcnt(0)" ::: "memory");
    __builtin_amdgcn_sched_barrier(0);
    G8_MFMA(1, 0)
    __builtin_amdgcn_s_barrier();
    asm volatile("" ::: "memory");

    if (st) {
      stage(t + 2, 0); stage(t + 2, 1);
      asm volatile("s_waitcnt vmcnt(8)" ::: "memory");
    } else if (t == nk - 2) {
      asm volatile("s_waitcnt vmcnt(0)" ::: "memory");
    }
    G8_MFMA(1, 1)
    __builtin_amdgcn_s_barrier();
    asm volatile("" ::: "memory");
  }

  if (jb.Cf) {
    #pragma unroll
    for (int mi = 0; mi < 8; mi++)
      #pragma unroll
      for (int jj = 0; jj < 4; jj++) {
        int m = m0 + wr * 128 + mi * 16 + lk * 4 + jj;
        float* drow = jb.Cf + (size_t)m * jb.c_stride + n0 + wc * 64;
        #pragma unroll
        for (int ni = 0; ni < 4; ni++) drow[ni * 16 + lr] = acc[mi][ni][jj];
      }
  } else {
    #pragma unroll
    for (int mi = 0; mi < 8; mi++)
      #pragma unroll
      for (int jj = 0; jj < 4; jj++) {
        int m = m0 + wr * 128 + mi * 16 + lk * 4 + jj;
        int crow = jb.c_base + m + ((m >> jb.c_lsh) * jb.c_lskip);
        bf16* drow = jb.Cb + (size_t)crow * jb.c_stride + n0 + wc * 64;
        #pragma unroll
        for (int ni = 0; ni < 4; ni++) drow[ni * 16 + lr] = f2bf(acc[mi][ni][jj]);
      }
  }
}

// ---------------------------------------------------------------------------
// Down split-K reduce: img out += p1+p2+p3+x ; txt out += q1..q7+x
// ---------------------------------------------------------------------------
__global__ __launch_bounds__(256) void reduce_down(
    float* __restrict__ oi, const float* __restrict__ a1,
    const float* __restrict__ a2, const float* __restrict__ a3,
    const float* __restrict__ xi, int n4i,
    float* __restrict__ ot, const float* __restrict__ b1,
    const float* __restrict__ b2, const float* __restrict__ b3,
    const float* __restrict__ b4, const float* __restrict__ b5,
    const float* __restrict__ b6, const float* __restrict__ b7,
    const float* __restrict__ xt, int n4t) {
  int tot = n4i + n4t;
  for (int idx = blockIdx.x * 256 + threadIdx.x; idx < tot; idx += gridDim.x * 256) {
    if (idx < n4i) {
      float4 d = ((const float4*)oi)[idx];
      float4 a = ((const float4*)a1)[idx];
      float4 b = ((const float4*)a2)[idx];
      float4 c = ((const float4*)a3)[idx];
      float4 e = ((const float4*)xi)[idx];
      ((float4*)oi)[idx] = make_float4(d.x + a.x + b.x + c.x + e.x,
                                       d.y + a.y + b.y + c.y + e.y,
                                       d.z + a.z + b.z + c.z + e.z,
                                       d.w + a.w + b.w + c.w + e.w);
    } else {
      int i = idx - n4i;
      float4 d = ((const float4*)ot)[i];
      float4 p1 = ((const float4*)b1)[i];
      float4 p2 = ((const float4*)b2)[i];
      float4 p3 = ((const float4*)b3)[i];
      float4 p4 = ((const float4*)b4)[i];
      float4 p5 = ((const float4*)b5)[i];
      float4 p6 = ((const float4*)b6)[i];
      float4 p7 = ((const float4*)b7)[i];
      float4 e = ((const float4*)xt)[i];
      ((float4*)ot)[i] = make_float4(
          d.x + p1.x + p2.x + p3.x + p4.x + p5.x + p6.x + p7.x + e.x,
          d.y + p1.y + p2.y + p3.y + p4.y + p5.y + p6.y + p7.y + e.y,
          d.z + p1.z + p2.z + p3.z + p4.z + p5.z + p6.z + p7.z + e.z,
          d.w + p1.w + p2.w + p3.w + p4.w + p5.w + p6.w + p7.w + e.w);
    }
  }
}

// ---------------------------------------------------------------------------
// In-place GELU(gate)*up over gu buffers: act written to gate half.
// ---------------------------------------------------------------------------
__global__ __launch_bounds__(256) void gelu_mul(bf16* __restrict__ gu_i,
                                                bf16* __restrict__ gu_t) {
  const int IMG_CH = 2048 * 8192 / 8;
  const int TXT_CH = 1024 * 4096 / 8;
  int idx = blockIdx.x * 256 + threadIdx.x;
  int total = IMG_CH + TXT_CH;
  if (idx >= total) return;
  bf16* base;
  int half, ci;
  if (idx < IMG_CH) { base = gu_i; half = 8192; ci = idx; }
  else              { base = gu_t; half = 4096; ci = idx - IMG_CH; }
  int rowlen = half * 2;
  int perrow = half / 8;
  int m = ci / perrow, n8 = ci - m * perrow;
  bf16* gp = base + (size_t)m * rowlen + n8 * 8;
  bf16* up = gp + half;
  bf16x8 g8 = *reinterpret_cast<const bf16x8*>(gp);
  bf16x8 u8 = *reinterpret_cast<const bf16x8*>(up);
  bf16x8 o8;
  #pragma unroll
  for (int i = 0; i < 8; i++) {
    float g = (float)g8[i], u = (float)u8[i];
    float t = tanhf(0.7978845608028654f * (g + 0.044715f * g * g * g));
    o8[i] = (__bf16)(0.5f * g * (1.f + t) * u);
  }
  *reinterpret_cast<bf16x8*>(gp) = o8;
}

// ---------------------------------------------------------------------------
// Fused: attention (blocks 0..767) + FFN weight transpose (blocks 768+).
// Attention: flash w/ softcap (no online max; logits bounded by +-50).
// ---------------------------------------------------------------------------
struct FAArgs {
  const bf16* q_all; const bf16* k_all; const bf16* vt; bf16* attn_o;
  TJob j[6]; int cum[7];
};

__global__ __launch_bounds__(256) void attn_wt(FAArgs A) {
  __shared__ __align__(16) char smem[41984];
  const int bid = blockIdx.x;
  const int tid = threadIdx.x;
  if (bid >= 768) {
    int rel = bid - 768;
    int ji = 0;
    while (ji < 5 && rel >= A.cum[ji + 1]) ji++;
    wt_body(A.j[ji], rel - A.cum[ji], tid, smem);
    return;
  }
  // ---- attention ----
  const int qt = bid % 24;
  const int n = (bid / 24) & 15;
  const int b = bid / 384;
  const int kv = n >> 1;
  const int w = tid >> 6, l = tid & 63;
  const int lr = l & 15, lk = l >> 4;
  bf16* Ksm = (bf16*)smem;                      // 64*128
  bf16* Vsm = (bf16*)(smem + 16384);            // 128*64
  typedef bf16 PsmRow[16][72];
  PsmRow* Psm = (PsmRow*)(smem + 32768);        // [4][16][72]

  bf16x8 qf[4];
  {
    int t = qt * 64 + w * 16 + lr;
    const bf16* qp = A.q_all + ((size_t)(b * TT + t) * NHQ + n) * HDM;
    #pragma unroll
    for (int kk = 0; kk < 4; kk++)
      qf[kk] = *reinterpret_cast<const bf16x8*>(qp + kk * 32 + lk * 8);
  }
  f32x4 acc_o[8];
  #pragma unroll
  for (int i = 0; i < 8; i++) acc_o[i] = (f32x4){0.f, 0.f, 0.f, 0.f};
  float den[4] = {0.f, 0.f, 0.f, 0.f};

  for (int st = 0; st < TT / 64; st++) {
    __syncthreads();
    #pragma unroll
    for (int i = 0; i < 4; i++) {
      int cb = (w * 4 + i) * 64;
      int c = cb + l;
      {
        int srow = c >> 4, c16 = c & 15;
        const bf16* g = A.k_all +
                        ((size_t)(b * TT + st * 64 + srow) * NKVH + kv) * HDM +
                        ((c16 ^ (srow & 7)) << 3);
        async_load16(g, Ksm + cb * 8);
      }
      {
        int hrow = c >> 3, c8 = c & 7;
        const bf16* g = A.vt + ((size_t)(b * NKVH + kv) * HDM + hrow) * TT +
                        st * 64 + ((c8 ^ (hrow & 7)) << 3);
        async_load16(g, Vsm + cb * 8);
      }
    }
    __syncthreads();
    #pragma unroll
    for (int sf = 0; sf < 4; sf++) {
      f32x4 s4 = (f32x4){0.f, 0.f, 0.f, 0.f};
      int sl = sf * 16 + lr;
      #pragma unroll
      for (int kk = 0; kk < 4; kk++) {
        int e = kk * 32 + lk * 8;
        bf16x8 kf = *reinterpret_cast<const bf16x8*>(
            Ksm + sl * 128 + ((((e >> 3) ^ (sl & 7))) << 3));
        s4 = mfma16(qf[kk], kf, s4);
      }
      #pragma unroll
      for (int j = 0; j < 4; j++) {
        float xv = s4[j];
        float tcap = tanhf(xv * 0.02f) * 50.f;
        float p = __expf(tcap);
        Psm[w][lk * 4 + j][sf * 16 + lr] = f2bf(p);
        p += __shfl_xor(p, 1);
        p += __shfl_xor(p, 2);
        p += __shfl_xor(p, 4);
        p += __shfl_xor(p, 8);
        den[j] += p;
      }
    }
    #pragma unroll
    for (int kk2 = 0; kk2 < 2; kk2++) {
      bf16x8 pa = *reinterpret_cast<const bf16x8*>(&Psm[w][lr][kk2 * 32 + lk * 8]);
      #pragma unroll
      for (int hf = 0; hf < 8; hf++) {
        int h = hf * 16 + lr;
        int e2 = kk2 * 32 + lk * 8;
        bf16x8 vb = *reinterpret_cast<const bf16x8*>(
            Vsm + h * 64 + ((((e2 >> 3) ^ (h & 7))) << 3));
        acc_o[hf] = mfma16(pa, vb, acc_o[hf]);
      }
    }
  }
  #pragma unroll
  for (int hf = 0; hf < 8; hf++)
    #pragma unroll
    for (int j = 0; j < 4; j++) {
      int t = qt * 64 + w * 16 + lk * 4 + j;
      float val = acc_o[hf][j] / den[j];
      A.attn_o[((size_t)(b * TT + t)) * (NHQ * HDM) + n * HDM + hf * 16 + lr] =
          f2bf(val);
    }
}

// ---------------------------------------------------------------------------
extern "C" void kernel_launch(void* const* d_in, const int* in_sizes, int n_in,
                              void* d_out, int out_size, void* d_ws,
                              size_t ws_size, hipStream_t stream) {
  const float* x_img = (const float*)d_in[0];
  const float* x_txt = (const float*)d_in[1];
  const float* sc_attn_i = (const float*)d_in[3];
  const float* wq_i = (const float*)d_in[4];
  const float* wk_i = (const float*)d_in[5];
  const float* wv_i = (const float*)d_in[6];
  const float* wo_i = (const float*)d_in[7];
  const float* sc_ffw_i = (const float*)d_in[8];
  const float* wg_i = (const float*)d_in[9];
  const float* wu_i = (const float*)d_in[10];
  const float* wd_i = (const float*)d_in[11];
  const float* sc_attn_t = (const float*)d_in[12];
  const float* wq_t = (const float*)d_in[13];
  const float* wk_t = (const float*)d_in[14];
  const float* wv_t = (const float*)d_in[15];
  const float* wo_t = (const float*)d_in[16];
  const float* sc_ffw_t = (const float*)d_in[17];
  const float* wg_t = (const float*)d_in[18];
  const float* wu_t = (const float*)d_in[19];
  const float* wd_t = (const float*)d_in[20];
  float* outp = (float*)d_out;
  float* outp_t = outp + (size_t)2 * 1024 * 2048;

  char* ws = (char*)d_ws;
  size_t off = 0;
  auto alloc = [&](size_t n) {
    char* p = ws + off;
    off += (n + 255) & ~(size_t)255;
    return p;
  };
  bf16* WqT_i = (bf16*)alloc((size_t)2048 * 2048 * 2);
  bf16* WkT_i = (bf16*)alloc((size_t)1024 * 2048 * 2);
  bf16* WvT_i = (bf16*)alloc((size_t)1024 * 2048 * 2);
  bf16* WoT_i = (bf16*)alloc((size_t)2048 * 2048 * 2);
  bf16* WguT_i = (bf16*)alloc((size_t)16384 * 2048 * 2);  // 64 MB
  bf16* WdT_i = (bf16*)alloc((size_t)2048 * 8192 * 2);
  bf16* WqT_t = (bf16*)alloc((size_t)2048 * 1024 * 2);
  bf16* WkT_t = (bf16*)alloc((size_t)1024 * 1024 * 2);
  bf16* WvT_t = (bf16*)alloc((size_t)1024 * 1024 * 2);
  bf16* WoT_t = (bf16*)alloc((size_t)1024 * 2048 * 2);
  bf16* WguT_t = (bf16*)alloc((size_t)8192 * 1024 * 2);   // 16 MB
  bf16* WdT_t = (bf16*)alloc((size_t)1024 * 4096 * 2);
  bf16* xn_i = (bf16*)alloc((size_t)2048 * 2048 * 2);
  bf16* xn_t = (bf16*)alloc((size_t)1024 * 1024 * 2);
  float* h_i = (float*)alloc((size_t)2048 * 2048 * 4);  // wo p0 img
  float* h_t = (float*)alloc((size_t)1024 * 1024 * 4);  // wo p0 txt
  char* S = (char*)alloc((size_t)84 * 1024 * 1024);
  (void)ws_size;

  const size_t MB = 1024 * 1024;
  bf16* q_all = (bf16*)S;
  bf16* k_all = (bf16*)(S + 12 * MB);
  bf16* v_all = (bf16*)(S + 18 * MB);
  bf16* vtr   = (bf16*)(S + 24 * MB);
  bf16* attn_o= (bf16*)(S + 30 * MB);
  float* wp1_i = (float*)S;
  float* wp1_t = (float*)(S + 16 * MB);
  bf16* gu_i  = (bf16*)S;
  bf16* gu_t  = (bf16*)(S + 64 * MB);
  float* dp1 = (float*)WguT_i;
  float* dp2 = (float*)((char*)WguT_i + 16 * MB);
  float* dp3 = (float*)((char*)WguT_i + 32 * MB);
  float* dt1 = (float*)((char*)WguT_i + 48 * MB);
  float* dt2 = (float*)((char*)WguT_i + 52 * MB);
  float* dt3 = (float*)((char*)WguT_i + 56 * MB);
  float* dt4 = (float*)((char*)WguT_i + 60 * MB);
  float* dt5 = (float*)WguT_t;
  float* dt6 = (float*)((char*)WguT_t + 4 * MB);
  float* dt7 = (float*)((char*)WguT_t + 8 * MB);

  (void)hipFuncSetAttribute(reinterpret_cast<const void*>(gemm8),
                            hipFuncAttributeMaxDynamicSharedMemorySize, 131072);

  // 1. transpose attn weights only (4608 blocks)
  TJobs tj;
  auto setj = [&](int idx, const float* s, bf16* d, int K, int N) {
    tj.j[idx].src = s; tj.j[idx].dst = d; tj.j[idx].K = K; tj.j[idx].N = N;
  };
  setj(0, wq_i, WqT_i, 2048, 2048);
  setj(1, wk_i, WkT_i, 2048, 1024);
  setj(2, wv_i, WvT_i, 2048, 1024);
  setj(3, wo_i, WoT_i, 2048, 2048);
  setj(4, wq_t, WqT_t, 1024, 2048);
  setj(5, wk_t, WkT_t, 1024, 1024);
  setj(6, wv_t, WvT_t, 1024, 1024);
  setj(7, wo_t, WoT_t, 2048, 1024);
  tj.cum[0] = 0;
  for (int i = 0; i < 8; i++)
    tj.cum[i + 1] = tj.cum[i] + (tj.j[i].K >> 6) * (tj.j[i].N >> 6);
  for (int i = 8; i < 14; i++) tj.cum[i + 1] = tj.cum[8];
  wt_transpose<<<tj.cum[8], 256, 0, stream>>>(tj);

  // 2. pre-attn RMSNorm
  rmsnorm_k<2><<<2048, 256, 0, stream>>>(x_img, sc_attn_i, xn_i);
  rmsnorm_k<1><<<1024, 256, 0, stream>>>(x_txt, sc_attn_t, xn_t);

  auto mk8b = [](const bf16* A, const bf16* B, bf16* Cb, int K, int N, int lda,
                 int ldb, int ab, int ash, int ask, int cb2, int csh, int csk,
                 int cstr) {
    G8Job g{};
    g.A = A; g.B = B; g.Cb = Cb; g.Cf = nullptr;
    g.K = K; g.N = N; g.lda = lda; g.ldb = ldb;
    g.a_base = ab; g.a_lsh = ash; g.a_lskip = ask;
    g.c_base = cb2; g.c_lsh = csh; g.c_lskip = csk; g.c_stride = cstr;
    return g;
  };
  auto mk8f = [](const bf16* A, const bf16* B, float* Cf, int K, int N, int lda,
                 int ldb, int ab, int ash, int ask, int cstr) {
    G8Job g{};
    g.A = A; g.B = B; g.Cb = nullptr; g.Cf = Cf;
    g.K = K; g.N = N; g.lda = lda; g.ldb = ldb;
    g.a_base = ab; g.a_lsh = ash; g.a_lskip = ask;
    g.c_base = 0; g.c_lsh = 30; g.c_lskip = 0; g.c_stride = cstr;
    return g;
  };
  auto launch8 = [&](G8Jobs& P, int nj, const int* Mt) {
    P.nj = nj;
    P.cum[0] = 0;
    for (int i = 0; i < nj; i++) P.cum[i + 1] = P.cum[i] + Mt[i] * (P.j[i].N >> 8);
    gemm8<<<P.cum[nj], 512, 131072, stream>>>(P);
  };

  // 3. QKV via gemm8
  {
    G8Jobs P;
    P.j[0] = mk8b(xn_i, WqT_i, q_all, 2048, 2048, 2048, 2048, 0, 30, 0, 0, 10, 512, 2048);
    P.j[1] = mk8b(xn_i, WkT_i, k_all, 2048, 1024, 2048, 2048, 0, 30, 0, 0, 10, 512, 1024);
    P.j[2] = mk8b(xn_i, WvT_i, v_all, 2048, 1024, 2048, 2048, 0, 30, 0, 0, 10, 512, 1024);
    P.j[3] = mk8b(xn_t, WqT_t, q_all, 1024, 2048, 1024, 1024, 0, 30, 0, 1024, 9, 1024, 2048);
    P.j[4] = mk8b(xn_t, WkT_t, k_all, 1024, 1024, 1024, 1024, 0, 30, 0, 1024, 9, 1024, 1024);
    P.j[5] = mk8b(xn_t, WvT_t, v_all, 1024, 1024, 1024, 1024, 0, 30, 0, 1024, 9, 1024, 1024);
    int Mt[6] = {8, 8, 8, 4, 4, 4};
    launch8(P, 6, Mt);
  }

  // 4. RoPE
  rope_inplace<<<12288, 256, 0, stream>>>(q_all, 4, 0.08838834764831845f);
  rope_inplace<<<6144, 256, 0, stream>>>(k_all, 3, 1.0f);

  // 5. V transpose
  transpose_v<<<dim3(24, 2, 16), 256, 0, stream>>>(v_all, vtr);

  // 6. attention + FFN weight transpose fused (768 + 15360 blocks)
  {
    FAArgs A;
    A.q_all = q_all; A.k_all = k_all; A.vt = vtr; A.attn_o = attn_o;
    auto setf = [&](int idx, const float* s, bf16* d, int K, int N) {
      A.j[idx].src = s; A.j[idx].dst = d; A.j[idx].K = K; A.j[idx].N = N;
    };
    setf(0, wg_i, WguT_i, 2048, 8192);
    setf(1, wu_i, WguT_i + (size_t)8192 * 2048, 2048, 8192);
    setf(2, wd_i, WdT_i, 8192, 2048);
    setf(3, wg_t, WguT_t, 1024, 4096);
    setf(4, wu_t, WguT_t + (size_t)4096 * 1024, 1024, 4096);
    setf(5, wd_t, WdT_t, 4096, 1024);
    A.cum[0] = 0;
    for (int i = 0; i < 6; i++)
      A.cum[i + 1] = A.cum[i] + (A.j[i].K >> 6) * (A.j[i].N >> 6);
    attn_wt<<<768 + A.cum[6], 256, 0, stream>>>(A);
  }

  // 7. WO split-K=2 (160 blocks): p0 -> h, p1 -> wp1
  {
    G8Jobs P;
    P.j[0] = mk8f(attn_o,        WoT_i,        h_i,   1024, 2048, 2048, 2048, 0, 10, 512, 2048);
    P.j[1] = mk8f(attn_o + 1024, WoT_i + 1024, wp1_i, 1024, 2048, 2048, 2048, 0, 10, 512, 2048);
    P.j[2] = mk8f(attn_o,        WoT_t,        h_t,   1024, 1024, 2048, 2048, 1024, 9, 1024, 1024);
    P.j[3] = mk8f(attn_o + 1024, WoT_t + 1024, wp1_t, 1024, 1024, 2048, 2048, 1024, 9, 1024, 1024);
    int Mt[4] = {8, 8, 4, 4};
    launch8(P, 4, Mt);
  }

  // 8. fused (p0+p1+x) RMSNorm -> xn
  rmsnorm2_k<2><<<2048, 256, 0, stream>>>(h_i, wp1_i, x_img, sc_ffw_i, xn_i);
  rmsnorm2_k<1><<<1024, 256, 0, stream>>>(h_t, wp1_t, x_txt, sc_ffw_t, xn_t);

  // 9. gate|up via gemm8 -> gu (bf16), single launch (640 blocks)
  {
    G8Jobs P;
    P.j[0] = mk8b(xn_i, WguT_i, gu_i, 2048, 16384, 2048, 2048, 0, 30, 0, 0, 30, 0, 16384);
    P.j[1] = mk8b(xn_t, WguT_t, gu_t, 1024, 8192, 1024, 1024, 0, 30, 0, 0, 30, 0, 8192);
    int Mt[2] = {8, 4};
    launch8(P, 2, Mt);
  }
  {
    int total = 2048 * 8192 / 8 + 1024 * 4096 / 8;
    gelu_mul<<<(total + 255) / 256, 256, 0, stream>>>(gu_i, gu_t);
  }

  // 10a. DOWN img split-4 (256 blocks, 1 clean round); p0 -> d_out
  {
    G8Jobs P;
    P.j[0] = mk8f(gu_i,        WdT_i,        outp, 2048, 2048, 16384, 8192, 0, 30, 0, 2048);
    P.j[1] = mk8f(gu_i + 2048, WdT_i + 2048, dp1,  2048, 2048, 16384, 8192, 0, 30, 0, 2048);
    P.j[2] = mk8f(gu_i + 4096, WdT_i + 4096, dp2,  2048, 2048, 16384, 8192, 0, 30, 0, 2048);
    P.j[3] = mk8f(gu_i + 6144, WdT_i + 6144, dp3,  2048, 2048, 16384, 8192, 0, 30, 0, 2048);
    int Mt[4] = {8, 8, 8, 8};
    launch8(P, 4, Mt);
  }
  // 10b. DOWN txt split-8 (128 blocks, short round 2); p0 -> d_out
  {
    G8Jobs P;
    float* dst[8] = {outp_t, dt1, dt2, dt3, dt4, dt5, dt6, dt7};
    for (int s = 0; s < 8; s++)
      P.j[s] = mk8f(gu_t + s * 512, WdT_t + s * 512, dst[s], 512, 1024, 8192,
                    4096, 0, 30, 0, 1024);
    int Mt[8] = {4, 4, 4, 4, 4, 4, 4, 4};
    launch8(P, 8, Mt);
  }
  reduce_down<<<2048, 256, 0, stream>>>(
      outp, dp1, dp2, dp3, x_img, 2048 * 2048 / 4,
      outp_t, dt1, dt2, dt3, dt4, dt5, dt6, dt7, x_txt, 1024 * 1024 / 4);
}

// Round 13
// 604.279 us; speedup vs baseline: 1.1155x; 1.0100x over previous
//
#include <hip/hip_runtime.h>
#include <hip/hip_bf16.h>

// MoE (img/txt mixture) transformer block for MI355X.
// Round 13: r12 structure (610us) + vectorized weight transpose:
// phase1 float4 coalesced reads -> LDS [64][72]; phase2 bf16x8 coalesced
// writes. 4x fewer global instructions; kills the issue-bound transpose.

typedef __hip_bfloat16 bf16;
typedef __attribute__((ext_vector_type(8))) __bf16 bf16x8;
typedef __attribute__((ext_vector_type(4))) float f32x4;

#define DEV __device__ __forceinline__

static constexpr int TT = 1536;
static constexpr int NHQ = 16, NKVH = 8, HDM = 128;

DEV void async_load16(const void* g, void* l) {
  typedef const __attribute__((address_space(1))) void* gas_t;
  typedef __attribute__((address_space(3))) void* las_t;
  __builtin_amdgcn_global_load_lds((gas_t)g, (las_t)l, 16, 0, 0);
}

DEV f32x4 mfma16(bf16x8 a, bf16x8 b, f32x4 c) {
  return __builtin_amdgcn_mfma_f32_16x16x32_bf16(a, b, c, 0, 0, 0);
}

DEV float bf2f(bf16 x) { return __bfloat162float(x); }
DEV bf16  f2bf(float x) { return __float2bfloat16(x); }

// ---------------------------------------------------------------------------
// Weight transpose+convert: f32 [K][N] -> bf16 [N][K]  (vectorized)
// ---------------------------------------------------------------------------
struct TJob { const float* src; bf16* dst; int K; int N; };
struct TJobs { TJob j[14]; int cum[15]; };

DEV void wt_body(const TJob& jb, int rel, int t, char* smem) {
  bf16* tile = (bf16*)smem;  // [64][72] bf16, rows 144B (16B-aligned)
  int ntc = jb.N >> 6;
  int tr = rel / ntc, tc = rel - tr * ntc;
  int r0 = tr << 6, c0 = tc << 6;  // r0: K offset, c0: N offset
  // phase 1: float4 along N (coalesced 16B), scatter 4 bf16 into tile[n][k]
  #pragma unroll
  for (int i = 0; i < 4; i++) {
    int g = i * 1024 + t * 4;
    int r = g >> 6, c = g & 63;
    float4 v = *reinterpret_cast<const float4*>(
        jb.src + (size_t)(r0 + r) * jb.N + c0 + c);
    tile[(c + 0) * 72 + r] = f2bf(v.x);
    tile[(c + 1) * 72 + r] = f2bf(v.y);
    tile[(c + 2) * 72 + r] = f2bf(v.z);
    tile[(c + 3) * 72 + r] = f2bf(v.w);
  }
  __syncthreads();
  // phase 2: read 16B contiguous from tile row, write bf16x8 along K
  #pragma unroll
  for (int i = 0; i < 2; i++) {
    int n = i * 32 + (t >> 3);
    int k0 = (t & 7) * 8;
    bf16x8 v = *reinterpret_cast<const bf16x8*>(tile + n * 72 + k0);
    *reinterpret_cast<bf16x8*>(jb.dst + (size_t)(c0 + n) * jb.K + r0 + k0) = v;
  }
}

__global__ __launch_bounds__(256) void wt_transpose(TJobs P) {
  __shared__ __align__(16) char smem[64 * 72 * 2];
  int bid = blockIdx.x;
  int ji = 0;
  while (ji < 13 && bid >= P.cum[ji + 1]) ji++;
  wt_body(P.j[ji], bid - P.cum[ji], threadIdx.x, smem);
}

// bf16 transpose for V: v_all [B*TT][NKVH*HDM] -> vt [B*NKVH][HDM][TT]
__global__ __launch_bounds__(256) void transpose_v(const bf16* __restrict__ v_all,
                                                   bf16* __restrict__ vt) {
  int st = blockIdx.x, ht = blockIdx.y, bk = blockIdx.z;
  int b = bk >> 3, kv = bk & 7;
  __shared__ bf16 tile[64][65];
  int t = threadIdx.x;
  int s0 = st * 64, h0 = ht * 64;
  #pragma unroll
  for (int i = 0; i < 16; i++) {
    int idx = i * 256 + t;
    int r = idx >> 6, c = idx & 63;
    tile[c][r] = v_all[((size_t)(b * TT + s0 + r) * NKVH + kv) * HDM + h0 + c];
  }
  __syncthreads();
  #pragma unroll
  for (int i = 0; i < 16; i++) {
    int idx = i * 256 + t;
    int r = idx >> 6, c = idx & 63;
    vt[((size_t)bk * HDM + h0 + r) * TT + s0 + c] = tile[r][c];
  }
}

// ---------------------------------------------------------------------------
// RMSNorm (single input)
// ---------------------------------------------------------------------------
template <int DV>
__global__ __launch_bounds__(256) void rmsnorm_k(const float* __restrict__ x,
                                                 const float* __restrict__ sc,
                                                 bf16* __restrict__ out) {
  const int D = DV * 1024;
  int row = blockIdx.x, t = threadIdx.x;
  const float4* xr = reinterpret_cast<const float4*>(x + (size_t)row * D);
  float4 v[DV];
  float ss = 0.f;
  #pragma unroll
  for (int i = 0; i < DV; i++) {
    v[i] = xr[t + i * 256];
    ss += v[i].x * v[i].x + v[i].y * v[i].y + v[i].z * v[i].z + v[i].w * v[i].w;
  }
  #pragma unroll
  for (int o = 1; o < 64; o <<= 1) ss += __shfl_xor(ss, o);
  __shared__ float red[4];
  if ((t & 63) == 0) red[t >> 6] = ss;
  __syncthreads();
  float r = rsqrtf((red[0] + red[1] + red[2] + red[3]) * (1.0f / D) + 1e-6f);
  bf16* orow = out + (size_t)row * D;
  #pragma unroll
  for (int i = 0; i < DV; i++) {
    int c = (t + i * 256) * 4;
    orow[c + 0] = f2bf(v[i].x * r * (1.f + sc[c + 0]));
    orow[c + 1] = f2bf(v[i].y * r * (1.f + sc[c + 1]));
    orow[c + 2] = f2bf(v[i].z * r * (1.f + sc[c + 2]));
    orow[c + 3] = f2bf(v[i].w * r * (1.f + sc[c + 3]));
  }
}

// ---------------------------------------------------------------------------
// RMSNorm over (p0+p1+x): fused wo split-K=2 reduce + pre-FFW norm
// ---------------------------------------------------------------------------
template <int DV>
__global__ __launch_bounds__(256) void rmsnorm2_k(
    const float* __restrict__ p0, const float* __restrict__ p1,
    const float* __restrict__ x, const float* __restrict__ sc,
    bf16* __restrict__ out) {
  const int D = DV * 1024;
  int row = blockIdx.x, t = threadIdx.x;
  size_t rb = (size_t)row * (D / 4);
  const float4* r0 = reinterpret_cast<const float4*>(p0) + rb;
  const float4* r1 = reinterpret_cast<const float4*>(p1) + rb;
  const float4* xr = reinterpret_cast<const float4*>(x) + rb;
  float4 v[DV];
  float ss = 0.f;
  #pragma unroll
  for (int i = 0; i < DV; i++) {
    int idx = t + i * 256;
    float4 a = r0[idx], b = r1[idx], e = xr[idx];
    v[i] = make_float4(a.x + b.x + e.x, a.y + b.y + e.y,
                       a.z + b.z + e.z, a.w + b.w + e.w);
    ss += v[i].x * v[i].x + v[i].y * v[i].y + v[i].z * v[i].z + v[i].w * v[i].w;
  }
  #pragma unroll
  for (int o = 1; o < 64; o <<= 1) ss += __shfl_xor(ss, o);
  __shared__ float red[4];
  if ((t & 63) == 0) red[t >> 6] = ss;
  __syncthreads();
  float r = rsqrtf((red[0] + red[1] + red[2] + red[3]) * (1.0f / D) + 1e-6f);
  bf16* orow = out + (size_t)row * D;
  #pragma unroll
  for (int i = 0; i < DV; i++) {
    int c = (t + i * 256) * 4;
    orow[c + 0] = f2bf(v[i].x * r * (1.f + sc[c + 0]));
    orow[c + 1] = f2bf(v[i].y * r * (1.f + sc[c + 1]));
    orow[c + 2] = f2bf(v[i].z * r * (1.f + sc[c + 2]));
    orow[c + 3] = f2bf(v[i].w * r * (1.f + sc[c + 3]));
  }
}

// ---------------------------------------------------------------------------
// RoPE in-place
// ---------------------------------------------------------------------------
__global__ __launch_bounds__(256) void rope_inplace(bf16* __restrict__ x, int lognh,
                                                    float scale) {
  int gid = blockIdx.x * 256 + threadIdx.x;
  int i = gid & 63;
  int rh = gid >> 6;
  int row = rh >> lognh;
  int pos = row >= TT ? row - TT : row;
  float fr = expf(-9.210340371976184f * ((float)(2 * i) * (1.0f / 128.0f)));
  float th = (float)pos * fr;
  float s, c;
  sincosf(th, &s, &c);
  bf16* p = x + (size_t)rh * HDM;
  float x1 = bf2f(p[i]), x2 = bf2f(p[i + 64]);
  p[i]      = f2bf((x1 * c - x2 * s) * scale);
  p[i + 64] = f2bf((x2 * c + x1 * s) * scale);
}

// ---------------------------------------------------------------------------
// 256x256 GEMM - r9 reduced-barrier K-loop (3 barriers/tile). PROVEN.
// ---------------------------------------------------------------------------
struct G8Job {
  const bf16* A; const bf16* B; bf16* Cb; float* Cf;
  int K, N, lda, ldb;
  int a_base, a_lsh, a_lskip;
  int c_base, c_lsh, c_lskip, c_stride;
};
struct G8Jobs { G8Job j[8]; int cum[9]; int nj; };

#define G8_MFMA(MH, NH)                                            \
  __builtin_amdgcn_s_setprio(1);                                   \
  _Pragma("unroll")                                                \
  for (int i = 0; i < 4; i++)                                      \
    _Pragma("unroll")                                              \
    for (int nj2 = 0; nj2 < 2; nj2++)                              \
      _Pragma("unroll")                                            \
      for (int kk = 0; kk < 2; kk++)                               \
        acc[(MH)*4 + i][(NH)*2 + nj2] = mfma16(                    \
            afr[i][kk], bfr[(NH)*2 + nj2][kk],                     \
            acc[(MH)*4 + i][(NH)*2 + nj2]);                        \
  __builtin_amdgcn_s_setprio(0);

__global__ __launch_bounds__(512, 2) void gemm8(G8Jobs P) {
  extern __shared__ __align__(16) bf16 lds8[];
  int bid = blockIdx.x;
  int ji = 0;
  while (ji < P.nj - 1 && bid >= P.cum[ji + 1]) ji++;
  const G8Job jb = P.j[ji];
  int rel = bid - P.cum[ji];
  int tn = jb.N >> 8;
  int bm = rel / tn, bn = rel - bm * tn;
  const int m0 = bm << 8, n0 = bn << 8;
  const int K = jb.K;
  const int nk = K >> 6;

  const int tid = threadIdx.x;
  const int w = tid >> 6, l = tid & 63;
  const int lr = l & 15, lk = l >> 4;
  const int wr = w >> 2, wc = w & 3;

  const int r0 = tid >> 3, sl0 = (tid & 7) ^ (r0 & 7);
  const int dst0 = (w * 64) * 8;
  const int dst1 = (512 + w * 64) * 8;

  auto stage = [&](int ht, int hq) {
    int k0 = ht << 6;
    bf16* ldsb = lds8 + ((ht & 1) * 32768 + hq * 8192);
    if (hq < 2) {
      int ma = m0 + hq * 128;
      int mr0 = ma + r0, mr1 = ma + 64 + r0;
      int pr0 = jb.a_base + mr0 + ((mr0 >> jb.a_lsh) * jb.a_lskip);
      int pr1 = jb.a_base + mr1 + ((mr1 >> jb.a_lsh) * jb.a_lskip);
      async_load16(jb.A + (size_t)pr0 * jb.lda + k0 + sl0 * 8, ldsb + dst0);
      async_load16(jb.A + (size_t)pr1 * jb.lda + k0 + sl0 * 8, ldsb + dst1);
    } else {
      int nb = n0 + (hq - 2) * 128;
      async_load16(jb.B + (size_t)(nb + r0) * jb.ldb + k0 + sl0 * 8, ldsb + dst0);
      async_load16(jb.B + (size_t)(nb + 64 + r0) * jb.ldb + k0 + sl0 * 8, ldsb + dst1);
    }
  };

  f32x4 acc[8][4];
  #pragma unroll
  for (int i = 0; i < 8; i++)
    #pragma unroll
    for (int j = 0; j < 4; j++) acc[i][j] = (f32x4){0.f, 0.f, 0.f, 0.f};

  const int s0 = ((0 * 4 + lk) ^ (lr & 7)) * 8;
  const int s1 = ((1 * 4 + lk) ^ (lr & 7)) * 8;
  const int browb = (wc & 1) * 64;

  #pragma unroll
  for (int hq = 0; hq < 4; hq++) stage(0, hq);
  #pragma unroll
  for (int hq = 0; hq < 4; hq++) stage(1, hq);
  asm volatile("s_waitcnt vmcnt(8)" ::: "memory");
  __builtin_amdgcn_s_barrier();
  asm volatile("" ::: "memory");

  bf16x8 afr[4][2], bfr[4][2];

  for (int t = 0; t < nk; t++) {
    const bf16* bufA = lds8 + (t & 1) * 32768 + wr * 8192;
    const bf16* bufB = lds8 + (t & 1) * 32768 + 16384 + (wc >> 1) * 8192;
    const bool st = (t + 2 < nk);

    #pragma unroll
    for (int i = 0; i < 4; i++) {
      int rb = (i * 16 + lr) * 64;
      afr[i][0] = *reinterpret_cast<const bf16x8*>(bufA + rb + s0);
      afr[i][1] = *reinterpret_cast<const bf16x8*>(bufA + rb + s1);
    }
    #pragma unroll
    for (int ni = 0; ni < 2; ni++) {
      int rb = (browb + ni * 16 + lr) * 64;
      bfr[ni][0] = *reinterpret_cast<const bf16x8*>(bufB + rb + s0);
      bfr[ni][1] = *reinterpret_cast<const bf16x8*>(bufB + rb + s1);
    }
    asm volatile("s_waitcnt lgkmcnt(0)" ::: "memory");
    __builtin_amdgcn_sched_barrier(0);
    G8_MFMA(0, 0)

    #pragma unroll
    for (int ni = 2; ni < 4; ni++) {
      int rb = (browb + ni * 16 + lr) * 64;
      bfr[ni][0] = *reinterpret_cast<const bf16x8*>(bufB + rb + s0);
      bfr[ni][1] = *reinterpret_cast<const bf16x8*>(bufB + rb + s1);
    }
    asm volatile("s_waitcnt lgkmcnt(0)" ::: "memory");
    __builtin_amdgcn_sched_barrier(0);
    G8_MFMA(0, 1)
    __builtin_amdgcn_s_barrier();
    asm volatile("" ::: "memory");

    #pragma unroll
    for (int i = 0; i < 4; i++) {
      int rb = ((i + 4) * 16 + lr) * 64;
      afr[i][0] = *reinterpret_cast<const bf16x8*>(bufA + rb + s0);
      afr[i][1] = *reinterpret_cast<const bf16x8*>(bufA + rb + s1);
    }
    if (st) { stage(t + 2, 2); stage(t + 2, 3); }
    asm volatile("s_waitcnt lgkmcnt(0)" ::: "memory");
    __builtin_amdgcn_sched_barrier(0);
    G8_MFMA(1, 0)
    __builtin_amdgcn_s_barrier();
    asm volatile("" ::: "memory");

    if (st) {
      stage(t + 2, 0); stage(t + 2, 1);
      asm volatile("s_waitcnt vmcnt(8)" ::: "memory");
    } else if (t == nk - 2) {
      asm volatile("s_waitcnt vmcnt(0)" ::: "memory");
    }
    G8_MFMA(1, 1)
    __builtin_amdgcn_s_barrier();
    asm volatile("" ::: "memory");
  }

  if (jb.Cf) {
    #pragma unroll
    for (int mi = 0; mi < 8; mi++)
      #pragma unroll
      for (int jj = 0; jj < 4; jj++) {
        int m = m0 + wr * 128 + mi * 16 + lk * 4 + jj;
        float* drow = jb.Cf + (size_t)m * jb.c_stride + n0 + wc * 64;
        #pragma unroll
        for (int ni = 0; ni < 4; ni++) drow[ni * 16 + lr] = acc[mi][ni][jj];
      }
  } else {
    #pragma unroll
    for (int mi = 0; mi < 8; mi++)
      #pragma unroll
      for (int jj = 0; jj < 4; jj++) {
        int m = m0 + wr * 128 + mi * 16 + lk * 4 + jj;
        int crow = jb.c_base + m + ((m >> jb.c_lsh) * jb.c_lskip);
        bf16* drow = jb.Cb + (size_t)crow * jb.c_stride + n0 + wc * 64;
        #pragma unroll
        for (int ni = 0; ni < 4; ni++) drow[ni * 16 + lr] = f2bf(acc[mi][ni][jj]);
      }
  }
}

// ---------------------------------------------------------------------------
// Down split-K reduce: img out += p1+p2+p3+x ; txt out += q1..q7+x
// ---------------------------------------------------------------------------
__global__ __launch_bounds__(256) void reduce_down(
    float* __restrict__ oi, const float* __restrict__ a1,
    const float* __restrict__ a2, const float* __restrict__ a3,
    const float* __restrict__ xi, int n4i,
    float* __restrict__ ot, const float* __restrict__ b1,
    const float* __restrict__ b2, const float* __restrict__ b3,
    const float* __restrict__ b4, const float* __restrict__ b5,
    const float* __restrict__ b6, const float* __restrict__ b7,
    const float* __restrict__ xt, int n4t) {
  int tot = n4i + n4t;
  for (int idx = blockIdx.x * 256 + threadIdx.x; idx < tot; idx += gridDim.x * 256) {
    if (idx < n4i) {
      float4 d = ((const float4*)oi)[idx];
      float4 a = ((const float4*)a1)[idx];
      float4 b = ((const float4*)a2)[idx];
      float4 c = ((const float4*)a3)[idx];
      float4 e = ((const float4*)xi)[idx];
      ((float4*)oi)[idx] = make_float4(d.x + a.x + b.x + c.x + e.x,
                                       d.y + a.y + b.y + c.y + e.y,
                                       d.z + a.z + b.z + c.z + e.z,
                                       d.w + a.w + b.w + c.w + e.w);
    } else {
      int i = idx - n4i;
      float4 d = ((const float4*)ot)[i];
      float4 p1 = ((const float4*)b1)[i];
      float4 p2 = ((const float4*)b2)[i];
      float4 p3 = ((const float4*)b3)[i];
      float4 p4 = ((const float4*)b4)[i];
      float4 p5 = ((const float4*)b5)[i];
      float4 p6 = ((const float4*)b6)[i];
      float4 p7 = ((const float4*)b7)[i];
      float4 e = ((const float4*)xt)[i];
      ((float4*)ot)[i] = make_float4(
          d.x + p1.x + p2.x + p3.x + p4.x + p5.x + p6.x + p7.x + e.x,
          d.y + p1.y + p2.y + p3.y + p4.y + p5.y + p6.y + p7.y + e.y,
          d.z + p1.z + p2.z + p3.z + p4.z + p5.z + p6.z + p7.z + e.z,
          d.w + p1.w + p2.w + p3.w + p4.w + p5.w + p6.w + p7.w + e.w);
    }
  }
}

// ---------------------------------------------------------------------------
// In-place GELU(gate)*up over gu buffers: act written to gate half.
// ---------------------------------------------------------------------------
__global__ __launch_bounds__(256) void gelu_mul(bf16* __restrict__ gu_i,
                                                bf16* __restrict__ gu_t) {
  const int IMG_CH = 2048 * 8192 / 8;
  const int TXT_CH = 1024 * 4096 / 8;
  int idx = blockIdx.x * 256 + threadIdx.x;
  int total = IMG_CH + TXT_CH;
  if (idx >= total) return;
  bf16* base;
  int half, ci;
  if (idx < IMG_CH) { base = gu_i; half = 8192; ci = idx; }
  else              { base = gu_t; half = 4096; ci = idx - IMG_CH; }
  int rowlen = half * 2;
  int perrow = half / 8;
  int m = ci / perrow, n8 = ci - m * perrow;
  bf16* gp = base + (size_t)m * rowlen + n8 * 8;
  bf16* up = gp + half;
  bf16x8 g8 = *reinterpret_cast<const bf16x8*>(gp);
  bf16x8 u8 = *reinterpret_cast<const bf16x8*>(up);
  bf16x8 o8;
  #pragma unroll
  for (int i = 0; i < 8; i++) {
    float g = (float)g8[i], u = (float)u8[i];
    float t = tanhf(0.7978845608028654f * (g + 0.044715f * g * g * g));
    o8[i] = (__bf16)(0.5f * g * (1.f + t) * u);
  }
  *reinterpret_cast<bf16x8*>(gp) = o8;
}

// ---------------------------------------------------------------------------
// Fused: attention (blocks 0..767) + FFN weight transpose (blocks 768+).
// ---------------------------------------------------------------------------
struct FAArgs {
  const bf16* q_all; const bf16* k_all; const bf16* vt; bf16* attn_o;
  TJob j[6]; int cum[7];
};

__global__ __launch_bounds__(256) void attn_wt(FAArgs A) {
  __shared__ __align__(16) char smem[41984];
  const int bid = blockIdx.x;
  const int tid = threadIdx.x;
  if (bid >= 768) {
    int rel = bid - 768;
    int ji = 0;
    while (ji < 5 && rel >= A.cum[ji + 1]) ji++;
    wt_body(A.j[ji], rel - A.cum[ji], tid, smem);
    return;
  }
  // ---- attention ----
  const int qt = bid % 24;
  const int n = (bid / 24) & 15;
  const int b = bid / 384;
  const int kv = n >> 1;
  const int w = tid >> 6, l = tid & 63;
  const int lr = l & 15, lk = l >> 4;
  bf16* Ksm = (bf16*)smem;
  bf16* Vsm = (bf16*)(smem + 16384);
  typedef bf16 PsmRow[16][72];
  PsmRow* Psm = (PsmRow*)(smem + 32768);

  bf16x8 qf[4];
  {
    int t = qt * 64 + w * 16 + lr;
    const bf16* qp = A.q_all + ((size_t)(b * TT + t) * NHQ + n) * HDM;
    #pragma unroll
    for (int kk = 0; kk < 4; kk++)
      qf[kk] = *reinterpret_cast<const bf16x8*>(qp + kk * 32 + lk * 8);
  }
  f32x4 acc_o[8];
  #pragma unroll
  for (int i = 0; i < 8; i++) acc_o[i] = (f32x4){0.f, 0.f, 0.f, 0.f};
  float den[4] = {0.f, 0.f, 0.f, 0.f};

  for (int st = 0; st < TT / 64; st++) {
    __syncthreads();
    #pragma unroll
    for (int i = 0; i < 4; i++) {
      int cb = (w * 4 + i) * 64;
      int c = cb + l;
      {
        int srow = c >> 4, c16 = c & 15;
        const bf16* g = A.k_all +
                        ((size_t)(b * TT + st * 64 + srow) * NKVH + kv) * HDM +
                        ((c16 ^ (srow & 7)) << 3);
        async_load16(g, Ksm + cb * 8);
      }
      {
        int hrow = c >> 3, c8 = c & 7;
        const bf16* g = A.vt + ((size_t)(b * NKVH + kv) * HDM + hrow) * TT +
                        st * 64 + ((c8 ^ (hrow & 7)) << 3);
        async_load16(g, Vsm + cb * 8);
      }
    }
    __syncthreads();
    #pragma unroll
    for (int sf = 0; sf < 4; sf++) {
      f32x4 s4 = (f32x4){0.f, 0.f, 0.f, 0.f};
      int sl = sf * 16 + lr;
      #pragma unroll
      for (int kk = 0; kk < 4; kk++) {
        int e = kk * 32 + lk * 8;
        bf16x8 kf = *reinterpret_cast<const bf16x8*>(
            Ksm + sl * 128 + ((((e >> 3) ^ (sl & 7))) << 3));
        s4 = mfma16(qf[kk], kf, s4);
      }
      #pragma unroll
      for (int j = 0; j < 4; j++) {
        float xv = s4[j];
        float tcap = tanhf(xv * 0.02f) * 50.f;
        float p = __expf(tcap);
        Psm[w][lk * 4 + j][sf * 16 + lr] = f2bf(p);
        p += __shfl_xor(p, 1);
        p += __shfl_xor(p, 2);
        p += __shfl_xor(p, 4);
        p += __shfl_xor(p, 8);
        den[j] += p;
      }
    }
    #pragma unroll
    for (int kk2 = 0; kk2 < 2; kk2++) {
      bf16x8 pa = *reinterpret_cast<const bf16x8*>(&Psm[w][lr][kk2 * 32 + lk * 8]);
      #pragma unroll
      for (int hf = 0; hf < 8; hf++) {
        int h = hf * 16 + lr;
        int e2 = kk2 * 32 + lk * 8;
        bf16x8 vb = *reinterpret_cast<const bf16x8*>(
            Vsm + h * 64 + ((((e2 >> 3) ^ (h & 7))) << 3));
        acc_o[hf] = mfma16(pa, vb, acc_o[hf]);
      }
    }
  }
  #pragma unroll
  for (int hf = 0; hf < 8; hf++)
    #pragma unroll
    for (int j = 0; j < 4; j++) {
      int t = qt * 64 + w * 16 + lk * 4 + j;
      float val = acc_o[hf][j] / den[j];
      A.attn_o[((size_t)(b * TT + t)) * (NHQ * HDM) + n * HDM + hf * 16 + lr] =
          f2bf(val);
    }
}

// ---------------------------------------------------------------------------
extern "C" void kernel_launch(void* const* d_in, const int* in_sizes, int n_in,
                              void* d_out, int out_size, void* d_ws,
                              size_t ws_size, hipStream_t stream) {
  const float* x_img = (const float*)d_in[0];
  const float* x_txt = (const float*)d_in[1];
  const float* sc_attn_i = (const float*)d_in[3];
  const float* wq_i = (const float*)d_in[4];
  const float* wk_i = (const float*)d_in[5];
  const float* wv_i = (const float*)d_in[6];
  const float* wo_i = (const float*)d_in[7];
  const float* sc_ffw_i = (const float*)d_in[8];
  const float* wg_i = (const float*)d_in[9];
  const float* wu_i = (const float*)d_in[10];
  const float* wd_i = (const float*)d_in[11];
  const float* sc_attn_t = (const float*)d_in[12];
  const float* wq_t = (const float*)d_in[13];
  const float* wk_t = (const float*)d_in[14];
  const float* wv_t = (const float*)d_in[15];
  const float* wo_t = (const float*)d_in[16];
  const float* sc_ffw_t = (const float*)d_in[17];
  const float* wg_t = (const float*)d_in[18];
  const float* wu_t = (const float*)d_in[19];
  const float* wd_t = (const float*)d_in[20];
  float* outp = (float*)d_out;
  float* outp_t = outp + (size_t)2 * 1024 * 2048;

  char* ws = (char*)d_ws;
  size_t off = 0;
  auto alloc = [&](size_t n) {
    char* p = ws + off;
    off += (n + 255) & ~(size_t)255;
    return p;
  };
  bf16* WqT_i = (bf16*)alloc((size_t)2048 * 2048 * 2);
  bf16* WkT_i = (bf16*)alloc((size_t)1024 * 2048 * 2);
  bf16* WvT_i = (bf16*)alloc((size_t)1024 * 2048 * 2);
  bf16* WoT_i = (bf16*)alloc((size_t)2048 * 2048 * 2);
  bf16* WguT_i = (bf16*)alloc((size_t)16384 * 2048 * 2);  // 64 MB
  bf16* WdT_i = (bf16*)alloc((size_t)2048 * 8192 * 2);
  bf16* WqT_t = (bf16*)alloc((size_t)2048 * 1024 * 2);
  bf16* WkT_t = (bf16*)alloc((size_t)1024 * 1024 * 2);
  bf16* WvT_t = (bf16*)alloc((size_t)1024 * 1024 * 2);
  bf16* WoT_t = (bf16*)alloc((size_t)1024 * 2048 * 2);
  bf16* WguT_t = (bf16*)alloc((size_t)8192 * 1024 * 2);   // 16 MB
  bf16* WdT_t = (bf16*)alloc((size_t)1024 * 4096 * 2);
  bf16* xn_i = (bf16*)alloc((size_t)2048 * 2048 * 2);
  bf16* xn_t = (bf16*)alloc((size_t)1024 * 1024 * 2);
  float* h_i = (float*)alloc((size_t)2048 * 2048 * 4);  // wo p0 img
  float* h_t = (float*)alloc((size_t)1024 * 1024 * 4);  // wo p0 txt
  char* S = (char*)alloc((size_t)84 * 1024 * 1024);
  (void)ws_size;

  const size_t MB = 1024 * 1024;
  bf16* q_all = (bf16*)S;
  bf16* k_all = (bf16*)(S + 12 * MB);
  bf16* v_all = (bf16*)(S + 18 * MB);
  bf16* vtr   = (bf16*)(S + 24 * MB);
  bf16* attn_o= (bf16*)(S + 30 * MB);
  float* wp1_i = (float*)S;
  float* wp1_t = (float*)(S + 16 * MB);
  bf16* gu_i  = (bf16*)S;
  bf16* gu_t  = (bf16*)(S + 64 * MB);
  float* dp1 = (float*)WguT_i;
  float* dp2 = (float*)((char*)WguT_i + 16 * MB);
  float* dp3 = (float*)((char*)WguT_i + 32 * MB);
  float* dt1 = (float*)((char*)WguT_i + 48 * MB);
  float* dt2 = (float*)((char*)WguT_i + 52 * MB);
  float* dt3 = (float*)((char*)WguT_i + 56 * MB);
  float* dt4 = (float*)((char*)WguT_i + 60 * MB);
  float* dt5 = (float*)WguT_t;
  float* dt6 = (float*)((char*)WguT_t + 4 * MB);
  float* dt7 = (float*)((char*)WguT_t + 8 * MB);

  (void)hipFuncSetAttribute(reinterpret_cast<const void*>(gemm8),
                            hipFuncAttributeMaxDynamicSharedMemorySize, 131072);

  // 1. transpose attn weights only (4608 blocks)
  TJobs tj;
  auto setj = [&](int idx, const float* s, bf16* d, int K, int N) {
    tj.j[idx].src = s; tj.j[idx].dst = d; tj.j[idx].K = K; tj.j[idx].N = N;
  };
  setj(0, wq_i, WqT_i, 2048, 2048);
  setj(1, wk_i, WkT_i, 2048, 1024);
  setj(2, wv_i, WvT_i, 2048, 1024);
  setj(3, wo_i, WoT_i, 2048, 2048);
  setj(4, wq_t, WqT_t, 1024, 2048);
  setj(5, wk_t, WkT_t, 1024, 1024);
  setj(6, wv_t, WvT_t, 1024, 1024);
  setj(7, wo_t, WoT_t, 2048, 1024);
  tj.cum[0] = 0;
  for (int i = 0; i < 8; i++)
    tj.cum[i + 1] = tj.cum[i] + (tj.j[i].K >> 6) * (tj.j[i].N >> 6);
  for (int i = 8; i < 14; i++) tj.cum[i + 1] = tj.cum[8];
  wt_transpose<<<tj.cum[8], 256, 0, stream>>>(tj);

  // 2. pre-attn RMSNorm
  rmsnorm_k<2><<<2048, 256, 0, stream>>>(x_img, sc_attn_i, xn_i);
  rmsnorm_k<1><<<1024, 256, 0, stream>>>(x_txt, sc_attn_t, xn_t);

  auto mk8b = [](const bf16* A, const bf16* B, bf16* Cb, int K, int N, int lda,
                 int ldb, int ab, int ash, int ask, int cb2, int csh, int csk,
                 int cstr) {
    G8Job g{};
    g.A = A; g.B = B; g.Cb = Cb; g.Cf = nullptr;
    g.K = K; g.N = N; g.lda = lda; g.ldb = ldb;
    g.a_base = ab; g.a_lsh = ash; g.a_lskip = ask;
    g.c_base = cb2; g.c_lsh = csh; g.c_lskip = csk; g.c_stride = cstr;
    return g;
  };
  auto mk8f = [](const bf16* A, const bf16* B, float* Cf, int K, int N, int lda,
                 int ldb, int ab, int ash, int ask, int cstr) {
    G8Job g{};
    g.A = A; g.B = B; g.Cb = nullptr; g.Cf = Cf;
    g.K = K; g.N = N; g.lda = lda; g.ldb = ldb;
    g.a_base = ab; g.a_lsh = ash; g.a_lskip = ask;
    g.c_base = 0; g.c_lsh = 30; g.c_lskip = 0; g.c_stride = cstr;
    return g;
  };
  auto launch8 = [&](G8Jobs& P, int nj, const int* Mt) {
    P.nj = nj;
    P.cum[0] = 0;
    for (int i = 0; i < nj; i++) P.cum[i + 1] = P.cum[i] + Mt[i] * (P.j[i].N >> 8);
    gemm8<<<P.cum[nj], 512, 131072, stream>>>(P);
  };

  // 3. QKV via gemm8
  {
    G8Jobs P;
    P.j[0] = mk8b(xn_i, WqT_i, q_all, 2048, 2048, 2048, 2048, 0, 30, 0, 0, 10, 512, 2048);
    P.j[1] = mk8b(xn_i, WkT_i, k_all, 2048, 1024, 2048, 2048, 0, 30, 0, 0, 10, 512, 1024);
    P.j[2] = mk8b(xn_i, WvT_i, v_all, 2048, 1024, 2048, 2048, 0, 30, 0, 0, 10, 512, 1024);
    P.j[3] = mk8b(xn_t, WqT_t, q_all, 1024, 2048, 1024, 1024, 0, 30, 0, 1024, 9, 1024, 2048);
    P.j[4] = mk8b(xn_t, WkT_t, k_all, 1024, 1024, 1024, 1024, 0, 30, 0, 1024, 9, 1024, 1024);
    P.j[5] = mk8b(xn_t, WvT_t, v_all, 1024, 1024, 1024, 1024, 0, 30, 0, 1024, 9, 1024, 1024);
    int Mt[6] = {8, 8, 8, 4, 4, 4};
    launch8(P, 6, Mt);
  }

  // 4. RoPE
  rope_inplace<<<12288, 256, 0, stream>>>(q_all, 4, 0.08838834764831845f);
  rope_inplace<<<6144, 256, 0, stream>>>(k_all, 3, 1.0f);

  // 5. V transpose
  transpose_v<<<dim3(24, 2, 16), 256, 0, stream>>>(v_all, vtr);

  // 6. attention + FFN weight transpose fused (768 + 15360 blocks)
  {
    FAArgs A;
    A.q_all = q_all; A.k_all = k_all; A.vt = vtr; A.attn_o = attn_o;
    auto setf = [&](int idx, const float* s, bf16* d, int K, int N) {
      A.j[idx].src = s; A.j[idx].dst = d; A.j[idx].K = K; A.j[idx].N = N;
    };
    setf(0, wg_i, WguT_i, 2048, 8192);
    setf(1, wu_i, WguT_i + (size_t)8192 * 2048, 2048, 8192);
    setf(2, wd_i, WdT_i, 8192, 2048);
    setf(3, wg_t, WguT_t, 1024, 4096);
    setf(4, wu_t, WguT_t + (size_t)4096 * 1024, 1024, 4096);
    setf(5, wd_t, WdT_t, 4096, 1024);
    A.cum[0] = 0;
    for (int i = 0; i < 6; i++)
      A.cum[i + 1] = A.cum[i] + (A.j[i].K >> 6) * (A.j[i].N >> 6);
    attn_wt<<<768 + A.cum[6], 256, 0, stream>>>(A);
  }

  // 7. WO split-K=2 (160 blocks): p0 -> h, p1 -> wp1
  {
    G8Jobs P;
    P.j[0] = mk8f(attn_o,        WoT_i,        h_i,   1024, 2048, 2048, 2048, 0, 10, 512, 2048);
    P.j[1] = mk8f(attn_o + 1024, WoT_i + 1024, wp1_i, 1024, 2048, 2048, 2048, 0, 10, 512, 2048);
    P.j[2] = mk8f(attn_o,        WoT_t,        h_t,   1024, 1024, 2048, 2048, 1024, 9, 1024, 1024);
    P.j[3] = mk8f(attn_o + 1024, WoT_t + 1024, wp1_t, 1024, 1024, 2048, 2048, 1024, 9, 1024, 1024);
    int Mt[4] = {8, 8, 4, 4};
    launch8(P, 4, Mt);
  }

  // 8. fused (p0+p1+x) RMSNorm -> xn
  rmsnorm2_k<2><<<2048, 256, 0, stream>>>(h_i, wp1_i, x_img, sc_ffw_i, xn_i);
  rmsnorm2_k<1><<<1024, 256, 0, stream>>>(h_t, wp1_t, x_txt, sc_ffw_t, xn_t);

  // 9. gate|up via gemm8 -> gu (bf16), single launch (640 blocks)
  {
    G8Jobs P;
    P.j[0] = mk8b(xn_i, WguT_i, gu_i, 2048, 16384, 2048, 2048, 0, 30, 0, 0, 30, 0, 16384);
    P.j[1] = mk8b(xn_t, WguT_t, gu_t, 1024, 8192, 1024, 1024, 0, 30, 0, 0, 30, 0, 8192);
    int Mt[2] = {8, 4};
    launch8(P, 2, Mt);
  }
  {
    int total = 2048 * 8192 / 8 + 1024 * 4096 / 8;
    gelu_mul<<<(total + 255) / 256, 256, 0, stream>>>(gu_i, gu_t);
  }

  // 10a. DOWN img split-4 (256 blocks, 1 clean round); p0 -> d_out
  {
    G8Jobs P;
    P.j[0] = mk8f(gu_i,        WdT_i,        outp, 2048, 2048, 16384, 8192, 0, 30, 0, 2048);
    P.j[1] = mk8f(gu_i + 2048, WdT_i + 2048, dp1,  2048, 2048, 16384, 8192, 0, 30, 0, 2048);
    P.j[2] = mk8f(gu_i + 4096, WdT_i + 4096, dp2,  2048, 2048, 16384, 8192, 0, 30, 0, 2048);
    P.j[3] = mk8f(gu_i + 6144, WdT_i + 6144, dp3,  2048, 2048, 16384, 8192, 0, 30, 0, 2048);
    int Mt[4] = {8, 8, 8, 8};
    launch8(P, 4, Mt);
  }
  // 10b. DOWN txt split-8 (128 blocks, short round 2); p0 -> d_out
  {
    G8Jobs P;
    float* dst[8] = {outp_t, dt1, dt2, dt3, dt4, dt5, dt6, dt7};
    for (int s = 0; s < 8; s++)
      P.j[s] = mk8f(gu_t + s * 512, WdT_t + s * 512, dst[s], 512, 1024, 8192,
                    4096, 0, 30, 0, 1024);
    int Mt[8] = {4, 4, 4, 4, 4, 4, 4, 4};
    launch8(P, 8, Mt);
  }
  reduce_down<<<2048, 256, 0, stream>>>(
      outp, dp1, dp2, dp3, x_img, 2048 * 2048 / 4,
      outp_t, dt1, dt2, dt3, dt4, dt5, dt6, dt7, x_txt, 1024 * 1024 / 4);
}